// Round 3
// baseline (4738.824 us; speedup 1.0000x reference)
//
#include <hip/hip_runtime.h>
#include <math.h>

#define NNODES   80000
#define IN_DIM   8
#define HID      128
#define HEADS    8
#define KH       16
#define NEDGE    1280000
#define NETOT    (NEDGE + NNODES)
#define NEGS     0.2f
#define EPSBN    1e-5f
#define BATCH    8
#define PERB     10000
#define NBLK     313            // ceil(80000/256)

__device__ __forceinline__ float lrelu(float v) { return v >= 0.f ? v : NEGS * v; }

__device__ __forceinline__ void edge_sd(const int* __restrict__ ei, int e, int& s, int& d) {
  if (e < NEDGE) { s = ei[e]; d = ei[NEDGE + e]; }
  else           { s = e - NEDGE; d = s; }
}

__device__ __forceinline__ void atomicMaxF(float* addr, float v) {
  if (v >= 0.f) atomicMax((int*)addr, __float_as_int(v));
  else          atomicMin((unsigned int*)addr, __float_as_uint(v));
}

// ---------- CSR build (by dst), once per call ----------
__global__ void k_zero_int(int* __restrict__ a, int n) {
  int i = blockIdx.x * blockDim.x + threadIdx.x;
  if (i < n) a[i] = 0;
}

__global__ void k_count(const int* __restrict__ ei, int* __restrict__ cnt) {
  int e = blockIdx.x * blockDim.x + threadIdx.x;
  if (e < NEDGE) atomicAdd(&cnt[ei[NEDGE + e]], 1);
}

// in-place exclusive scan, stage 1: per-block scan + block sums
__global__ void k_scan1(int* __restrict__ data, int* __restrict__ bsum) {
  __shared__ int tmp[256];
  int i = blockIdx.x * 256 + threadIdx.x;
  int v = (i < NNODES) ? data[i] : 0;
  tmp[threadIdx.x] = v;
  __syncthreads();
  for (int off = 1; off < 256; off <<= 1) {
    int t = (threadIdx.x >= off) ? tmp[threadIdx.x - off] : 0;
    __syncthreads();
    tmp[threadIdx.x] += t;
    __syncthreads();
  }
  if (i < NNODES) data[i] = tmp[threadIdx.x] - v;   // exclusive
  if (threadIdx.x == 255) bsum[blockIdx.x] = tmp[255];
}

// stage 2: exclusive scan of block sums (single block, 512 >= NBLK)
__global__ void k_scan2(int* __restrict__ bsum, int* __restrict__ bex) {
  __shared__ int tmp[512];
  int v = (threadIdx.x < NBLK) ? bsum[threadIdx.x] : 0;
  tmp[threadIdx.x] = v;
  __syncthreads();
  for (int off = 1; off < 512; off <<= 1) {
    int t = (threadIdx.x >= off) ? tmp[threadIdx.x - off] : 0;
    __syncthreads();
    tmp[threadIdx.x] += t;
    __syncthreads();
  }
  if (threadIdx.x < NBLK) bex[threadIdx.x] = tmp[threadIdx.x] - v;
}

// stage 3: add block offsets; set rowptr[NNODES]
__global__ void k_scan3(int* __restrict__ data, const int* __restrict__ bex) {
  int i = blockIdx.x * 256 + threadIdx.x;
  if (i < NNODES) data[i] += bex[blockIdx.x];
  if (i == 0) data[NNODES] = NEDGE;
}

__global__ void k_fill(const int* __restrict__ ei, const int* __restrict__ rowptr,
                       int* __restrict__ fc, int* __restrict__ elist) {
  int e = blockIdx.x * blockDim.x + threadIdx.x;
  if (e >= NEDGE) return;
  int d = ei[NEDGE + e];
  int pos = rowptr[d] + atomicAdd(&fc[d], 1);
  elist[pos] = e;
}

// ---------- layer-1 GEMM (K=8): W1 in registers ----------
__global__ void k_gemm_in(const float* __restrict__ x, const float* __restrict__ W,
                          float* __restrict__ h) {
  int tid = blockIdx.x * blockDim.x + threadIdx.x;
  int tx = tid & 15;
  int c0 = tx * 8;
  float4 wv[16];
#pragma unroll
  for (int j = 0; j < 8; j++) {
    wv[j * 2 + 0] = *(const float4*)(W + (size_t)(c0 + j) * IN_DIM);
    wv[j * 2 + 1] = *(const float4*)(W + (size_t)(c0 + j) * IN_DIM + 4);
  }
  int stride = (gridDim.x * blockDim.x) >> 4;
  for (int n = tid >> 4; n < NNODES; n += stride) {
    float4 x0 = *(const float4*)(x + (size_t)n * IN_DIM);
    float4 x1 = *(const float4*)(x + (size_t)n * IN_DIM + 4);
    float o[8];
#pragma unroll
    for (int j = 0; j < 8; j++) {
      float4 a = wv[j * 2], b = wv[j * 2 + 1];
      o[j] = x0.x*a.x + x0.y*a.y + x0.z*a.z + x0.w*a.w
           + x1.x*b.x + x1.y*b.y + x1.z*b.z + x1.w*b.w;
    }
    float4* hp = (float4*)(h + (size_t)n * HID + c0);
    hp[0] = make_float4(o[0], o[1], o[2], o[3]);
    hp[1] = make_float4(o[4], o[5], o[6], o[7]);
  }
}

// ---------- 128x128 GEMM: 8x8 per thread, W^T in LDS ----------
#define GB_NODES 128
__global__ __launch_bounds__(256, 2)
void k_gemm128_t(const float* __restrict__ x, const float* __restrict__ W,
                 float* __restrict__ h) {
  __shared__ float sw[HID][HID + 4];
  int tid = threadIdx.x;
  for (int idx = tid * 4; idx < HID * HID; idx += 256 * 4) {
    int c = idx >> 7, k = idx & 127;
    float4 w = *(const float4*)(W + (size_t)c * HID + k);
    sw[k + 0][c] = w.x; sw[k + 1][c] = w.y; sw[k + 2][c] = w.z; sw[k + 3][c] = w.w;
  }
  __syncthreads();
  int tx = tid & 15, ty = tid >> 4;
  int n0 = blockIdx.x * GB_NODES + ty * 8;
  int c0 = tx * 8;
  float acc[8][8];
#pragma unroll
  for (int i = 0; i < 8; i++)
#pragma unroll
    for (int j = 0; j < 8; j++) acc[i][j] = 0.f;

  const float* xp = x + (size_t)n0 * HID;
  for (int kk = 0; kk < HID; kk += 4) {
    float4 xv[8];
#pragma unroll
    for (int i = 0; i < 8; i++) xv[i] = *(const float4*)(xp + (size_t)i * HID + kk);
#pragma unroll
    for (int k4 = 0; k4 < 4; k4++) {
      float4 w0 = *(const float4*)&sw[kk + k4][c0];
      float4 w1 = *(const float4*)&sw[kk + k4][c0 + 4];
      float wj[8] = { w0.x, w0.y, w0.z, w0.w, w1.x, w1.y, w1.z, w1.w };
#pragma unroll
      for (int i = 0; i < 8; i++) {
        const float* xe = (const float*)&xv[i];
        float xs = xe[k4];
#pragma unroll
        for (int j = 0; j < 8; j++) acc[i][j] += xs * wj[j];
      }
    }
  }
#pragma unroll
  for (int i = 0; i < 8; i++) {
    float4* hp = (float4*)(h + (size_t)(n0 + i) * HID + c0);
    hp[0] = make_float4(acc[i][0], acc[i][1], acc[i][2], acc[i][3]);
    hp[1] = make_float4(acc[i][4], acc[i][5], acc[i][6], acc[i][7]);
  }
}

__global__ void k_att_node(const float* __restrict__ h, const float* __restrict__ att,
                           float* __restrict__ aL, float* __restrict__ aR) {
  __shared__ float satt[HEADS * 2 * KH];
  for (int i = threadIdx.x; i < HEADS * 2 * KH; i += blockDim.x) satt[i] = att[i];
  __syncthreads();
  int total = NNODES * HEADS;
  for (int idx = blockIdx.x * blockDim.x + threadIdx.x; idx < total;
       idx += gridDim.x * blockDim.x) {
    int n = idx >> 3, hd = idx & 7;
    const float* hp  = h + (size_t)n * HID + hd * KH;
    const float* aLw = satt + hd * 2 * KH;
    const float* aRw = aLw + KH;
    float sl = 0.f, sr = 0.f;
#pragma unroll
    for (int c = 0; c < KH; c++) { float v = hp[c]; sl += v * aLw[c]; sr += v * aRw[c]; }
    aL[idx] = sl; aR[idx] = sr;
  }
}

__global__ void k_fill_neginf(float* __restrict__ a, int n) {
  for (int i = blockIdx.x * blockDim.x + threadIdx.x; i < n; i += gridDim.x * blockDim.x)
    a[i] = -INFINITY;
}

// pass 1: per-edge a (vectorized), store real-edge a, atomic max by src
__global__ void k_edge_max(const int* __restrict__ ei, const float* __restrict__ aL,
                           const float* __restrict__ aR, float* __restrict__ amax,
                           float* __restrict__ ae) {
  int e = blockIdx.x * blockDim.x + threadIdx.x;
  if (e >= NETOT) return;
  int s, d; edge_sd(ei, e, s, d);
  float4 l0 = *(const float4*)(aL + (size_t)d * 8);
  float4 l1 = *(const float4*)(aL + (size_t)d * 8 + 4);
  float4 r0 = *(const float4*)(aR + (size_t)s * 8);
  float4 r1 = *(const float4*)(aR + (size_t)s * 8 + 4);
  float a[8] = { lrelu(l0.x + r0.x), lrelu(l0.y + r0.y), lrelu(l0.z + r0.z), lrelu(l0.w + r0.w),
                 lrelu(l1.x + r1.x), lrelu(l1.y + r1.y), lrelu(l1.z + r1.z), lrelu(l1.w + r1.w) };
  if (e < NEDGE) {
    float4* ap = (float4*)(ae + (size_t)e * 8);
    ap[0] = make_float4(a[0], a[1], a[2], a[3]);
    ap[1] = make_float4(a[4], a[5], a[6], a[7]);
  }
#pragma unroll
  for (int k = 0; k < 8; k++) atomicMaxF(&amax[s * 8 + k], a[k]);
}

// pass 2: atomic sum of exp by src
__global__ void k_edge_den(const int* __restrict__ ei, const float* __restrict__ aL,
                           const float* __restrict__ aR, const float* __restrict__ amax,
                           float* __restrict__ den, const float* __restrict__ ae) {
  int e = blockIdx.x * blockDim.x + threadIdx.x;
  if (e >= NETOT) return;
  int s, d; edge_sd(ei, e, s, d);
  float a[8];
  if (e < NEDGE) {
    float4 a0 = *(const float4*)(ae + (size_t)e * 8);
    float4 a1 = *(const float4*)(ae + (size_t)e * 8 + 4);
    a[0]=a0.x; a[1]=a0.y; a[2]=a0.z; a[3]=a0.w; a[4]=a1.x; a[5]=a1.y; a[6]=a1.z; a[7]=a1.w;
  } else {
    float4 l0 = *(const float4*)(aL + (size_t)s * 8);
    float4 l1 = *(const float4*)(aL + (size_t)s * 8 + 4);
    float4 r0 = *(const float4*)(aR + (size_t)s * 8);
    float4 r1 = *(const float4*)(aR + (size_t)s * 8 + 4);
    a[0]=lrelu(l0.x+r0.x); a[1]=lrelu(l0.y+r0.y); a[2]=lrelu(l0.z+r0.z); a[3]=lrelu(l0.w+r0.w);
    a[4]=lrelu(l1.x+r1.x); a[5]=lrelu(l1.y+r1.y); a[6]=lrelu(l1.z+r1.z); a[7]=lrelu(l1.w+r1.w);
  }
  float4 m0 = *(const float4*)(amax + (size_t)s * 8);
  float4 m1 = *(const float4*)(amax + (size_t)s * 8 + 4);
  float m[8] = { m0.x, m0.y, m0.z, m0.w, m1.x, m1.y, m1.z, m1.w };
#pragma unroll
  for (int k = 0; k < 8; k++) atomicAdd(&den[s * 8 + k], expf(a[k] - m[k]));
}

// pass 2.5: finalize alpha for real edges (in place)
__global__ void k_edge_alpha(const int* __restrict__ ei, const float* __restrict__ amax,
                             const float* __restrict__ den, float* __restrict__ ae) {
  int e = blockIdx.x * blockDim.x + threadIdx.x;
  if (e >= NEDGE) return;
  int s = ei[e];
  float4 a0 = *(const float4*)(ae + (size_t)e * 8);
  float4 a1 = *(const float4*)(ae + (size_t)e * 8 + 4);
  float4 m0 = *(const float4*)(amax + (size_t)s * 8);
  float4 m1 = *(const float4*)(amax + (size_t)s * 8 + 4);
  float4 d0 = *(const float4*)(den + (size_t)s * 8);
  float4 d1 = *(const float4*)(den + (size_t)s * 8 + 4);
  a0.x = expf(a0.x - m0.x) / (d0.x + 1e-16f);
  a0.y = expf(a0.y - m0.y) / (d0.y + 1e-16f);
  a0.z = expf(a0.z - m0.z) / (d0.z + 1e-16f);
  a0.w = expf(a0.w - m0.w) / (d0.w + 1e-16f);
  a1.x = expf(a1.x - m1.x) / (d1.x + 1e-16f);
  a1.y = expf(a1.y - m1.y) / (d1.y + 1e-16f);
  a1.z = expf(a1.z - m1.z) / (d1.z + 1e-16f);
  a1.w = expf(a1.w - m1.w) / (d1.w + 1e-16f);
  float4* ap = (float4*)(ae + (size_t)e * 8);
  ap[0] = a0; ap[1] = a1;
}

// pass 3: GATHER aggregation via dst-CSR; fuse bias+relu; y -> yout
__global__ __launch_bounds__(256)
void k_agg_gather(const int* __restrict__ ei, const int* __restrict__ rowptr,
                  const int* __restrict__ elist, const float* __restrict__ ae,
                  const float* __restrict__ aL, const float* __restrict__ aR,
                  const float* __restrict__ amax, const float* __restrict__ den,
                  const float* __restrict__ h, const float* __restrict__ bias,
                  float* __restrict__ yout) {
  int node = blockIdx.x * 2 + (threadIdx.x >> 7);
  if (node >= NNODES) return;
  int c = threadIdx.x & 127;
  int hd = c >> 4;
  int sh = node * 8 + hd;
  // self-loop contribution (alpha recomputed inline)
  float a = lrelu(aL[sh] + aR[sh]);
  float alpha = expf(a - amax[sh]) / (den[sh] + 1e-16f);
  float acc = alpha * h[(size_t)node * HID + c];
  int j0 = rowptr[node], j1 = rowptr[node + 1];
  for (int j = j0; j < j1; j++) {
    int e = elist[j];
    int s = ei[e];
    float al = ae[(size_t)e * 8 + hd];
    acc += al * h[(size_t)s * HID + c];
  }
  float v = acc + bias[c];
  yout[(size_t)node * HID + c] = v > 0.f ? v : 0.f;
}

// BN statistics (read-only over y)
__global__ void k_bnstats(const float* __restrict__ y, double* __restrict__ bnsum,
                          double* __restrict__ bnsq) {
  int c = threadIdx.x;
  float s = 0.f, sq = 0.f;
  for (int n = blockIdx.x; n < NNODES; n += gridDim.x) {
    float v = y[(size_t)n * HID + c];
    s += v; sq += v * v;
  }
  atomicAdd(&bnsum[c], (double)s);
  atomicAdd(&bnsq[c], (double)sq);
}

__global__ void k_bnfinal(const double* __restrict__ bnsum, const double* __restrict__ bnsq,
                          const float* __restrict__ g, const float* __restrict__ be,
                          float* __restrict__ scale, float* __restrict__ shift) {
  int c = threadIdx.x;
  double mean = bnsum[c] / (double)NNODES;
  double var  = bnsq[c] / (double)NNODES - mean * mean;
  float rs = (float)(1.0 / sqrt(var + (double)EPSBN));
  float sc = g[c] * rs;
  scale[c] = sc;
  shift[c] = be[c] - (float)mean * sc;
}

__global__ void k_bnapply(const float* __restrict__ y, const float* __restrict__ scale,
                          const float* __restrict__ shift, float* __restrict__ xo) {
  int total = NNODES * HID;
  for (int idx = blockIdx.x * blockDim.x + threadIdx.x; idx < total;
       idx += gridDim.x * blockDim.x) {
    int c = idx & 127;
    xo[idx] = lrelu(y[idx] * scale[c] + shift[c]);
  }
}

__global__ void k_pmean(const float* __restrict__ xf, const float* __restrict__ p_,
                        float* __restrict__ xgsum) {
  int b = blockIdx.y, c = threadIdx.x;
  float p = p_[0];
  int rows_per = (PERB + gridDim.x - 1) / gridDim.x;
  int r0 = blockIdx.x * rows_per;
  int r1 = r0 + rows_per; if (r1 > PERB) r1 = PERB;
  float acc = 0.f;
  for (int i = r0; i < r1; i++) {
    float v = xf[((size_t)b * PERB + i) * HID + c];
    v = fminf(fmaxf(v, 0.f), 100.f);
    acc += powf(v, p);
  }
  atomicAdd(&xgsum[b * HID + c], acc);
}

__global__ void k_head(const float* __restrict__ xgsum, const float* __restrict__ p_,
                       const float* __restrict__ Wg, const float* __restrict__ bg,
                       float* __restrict__ out) {
  __shared__ float sxg[HID];
  __shared__ float red[HID];
  int b = blockIdx.x, c = threadIdx.x;
  float p = p_[0];
  float m = xgsum[b * HID + c] / (float)PERB;
  m = fminf(fmaxf(m, 0.f), 100.f);
  sxg[c] = powf(m, 1.0f / p);
  __syncthreads();
  float l0 = 0.f, l1 = 0.f;
  for (int j = 0; j < 2; j++) {
    red[c] = sxg[c] * Wg[j * HID + c];
    __syncthreads();
    for (int off = 64; off > 0; off >>= 1) {
      if (c < off) red[c] += red[c + off];
      __syncthreads();
    }
    if (c == 0) { if (j == 0) l0 = red[0] + bg[0]; else l1 = red[0] + bg[1]; }
    __syncthreads();
  }
  if (c == 0) {
    out[b * 2 + 0] = l0;
    out[b * 2 + 1] = l1;
    out[2 * BATCH + b] = (l1 > l0) ? 1.0f : 0.0f;
  }
}

extern "C" void kernel_launch(void* const* d_in, const int* in_sizes, int n_in,
                              void* d_out, int out_size, void* d_ws, size_t ws_size,
                              hipStream_t stream) {
  (void)in_sizes; (void)n_in; (void)out_size; (void)ws_size;
  const float* x    = (const float*)d_in[0];
  const int*   ei   = (const int*)d_in[1];
  const float* Wl[3]   = { (const float*)d_in[2],  (const float*)d_in[7],  (const float*)d_in[12] };
  const float* attl[3] = { (const float*)d_in[3],  (const float*)d_in[8],  (const float*)d_in[13] };
  const float* bl[3]   = { (const float*)d_in[4],  (const float*)d_in[9],  (const float*)d_in[14] };
  const float* gl[3]   = { (const float*)d_in[5],  (const float*)d_in[10], (const float*)d_in[15] };
  const float* bel[3]  = { (const float*)d_in[6],  (const float*)d_in[11], (const float*)d_in[16] };
  const float* p    = (const float*)d_in[17];
  const float* Wg   = (const float*)d_in[18];
  const float* bg   = (const float*)d_in[19];
  float* out = (float*)d_out;

  float* ws   = (float*)d_ws;
  float* h    = ws;                                  // N*128
  float* agg  = h    + (size_t)NNODES * HID;         // N*128  (= y after gather)
  float* xbuf = agg  + (size_t)NNODES * HID;         // N*128  (aliased as ae during edge phase)
  float* aL   = xbuf + (size_t)NNODES * HID;         // N*8
  float* aR   = aL   + (size_t)NNODES * HEADS;
  float* amax = aR   + (size_t)NNODES * HEADS;
  float* den  = amax + (size_t)NNODES * HEADS;
  double* bnsum = (double*)(den + (size_t)NNODES * HEADS);
  double* bnsq  = bnsum + HID;
  float* scale  = (float*)(bnsq + HID);
  float* shift  = scale + HID;
  float* xgsum  = shift + HID;                       // 8*128
  // CSR scratch (built once per call; graph fixed across layers)
  int* rowptr = (int*)(xgsum + BATCH * HID);         // NNODES+1 (doubles as cnt)
  int* fc     = rowptr + (NNODES + 1);               // NNODES
  int* bsum   = fc + NNODES;                         // NBLK
  int* bex    = bsum + NBLK;                         // NBLK
  int* elist  = bex + NBLK;                          // NEDGE
  float* ae = xbuf;                                  // NEDGE*8 == N*128 exactly

  // ---- build dst-CSR ----
  k_zero_int<<<(2 * NNODES + 256) / 256, 256, 0, stream>>>(rowptr, 2 * NNODES + 1);
  k_count<<<(NEDGE + 255) / 256, 256, 0, stream>>>(ei, rowptr);
  k_scan1<<<NBLK, 256, 0, stream>>>(rowptr, bsum);
  k_scan2<<<1, 512, 0, stream>>>(bsum, bex);
  k_scan3<<<NBLK, 256, 0, stream>>>(rowptr, bex);
  k_fill<<<(NEDGE + 255) / 256, 256, 0, stream>>>(ei, rowptr, fc, elist);

  for (int layer = 0; layer < 3; layer++) {
    const float* xin = (layer == 0) ? x : xbuf;
    if (layer == 0) k_gemm_in<<<2048, 256, 0, stream>>>(xin, Wl[0], h);
    else            k_gemm128_t<<<NNODES / GB_NODES, 256, 0, stream>>>(xin, Wl[layer], h);

    k_att_node<<<2500, 256, 0, stream>>>(h, attl[layer], aL, aR);

    hipMemsetAsync(den, 0, sizeof(float) * (size_t)NNODES * HEADS, stream);
    k_fill_neginf<<<2500, 256, 0, stream>>>(amax, NNODES * HEADS);

    k_edge_max<<<(NETOT + 255) / 256, 256, 0, stream>>>(ei, aL, aR, amax, ae);
    k_edge_den<<<(NETOT + 255) / 256, 256, 0, stream>>>(ei, aL, aR, amax, den, ae);
    k_edge_alpha<<<(NEDGE + 255) / 256, 256, 0, stream>>>(ei, amax, den, ae);
    k_agg_gather<<<NNODES / 2, 256, 0, stream>>>(ei, rowptr, elist, ae, aL, aR, amax, den,
                                                 h, bl[layer], agg);

    hipMemsetAsync(bnsum, 0, sizeof(double) * HID * 2, stream);
    k_bnstats<<<1024, 128, 0, stream>>>(agg, bnsum, bnsq);
    k_bnfinal<<<1, 128, 0, stream>>>(bnsum, bnsq, gl[layer], bel[layer], scale, shift);
    k_bnapply<<<4096, 256, 0, stream>>>(agg, scale, shift, xbuf);
  }

  hipMemsetAsync(xgsum, 0, sizeof(float) * BATCH * HID, stream);
  k_pmean<<<dim3(32, BATCH), 128, 0, stream>>>(xbuf, p, xgsum);
  k_head<<<BATCH, 128, 0, stream>>>(xgsum, p, Wg, bg, out);
}

// Round 7
// 1734.015 us; speedup vs baseline: 2.7329x; 2.7329x over previous
//
#include <hip/hip_runtime.h>
#include <math.h>

#define NNODES   80000
#define IN_DIM   8
#define HID      128
#define HEADS    8
#define KH       16
#define NEDGE    1280000
#define NETOT    (NEDGE + NNODES)
#define NEGS     0.2f
#define EPSBN    1e-5f
#define BATCH    8
#define PERB     10000
#define NBLK     313            // ceil(80000/256)

__device__ __forceinline__ float lrelu(float v) { return v >= 0.f ? v : NEGS * v; }

// ---------- CSR build (dst and src), once per call ----------
__global__ void k_count2(const int* __restrict__ ei, int* __restrict__ cntD,
                         int* __restrict__ cntS) {
  int e = blockIdx.x * blockDim.x + threadIdx.x;
  if (e >= NEDGE) return;
  atomicAdd(&cntD[ei[NEDGE + e]], 1);
  atomicAdd(&cntS[ei[e]], 1);
}

// in-place exclusive scan, stage 1: per-block scan + block sums
__global__ void k_scan1(int* __restrict__ data, int* __restrict__ bsum) {
  __shared__ int tmp[256];
  int i = blockIdx.x * 256 + threadIdx.x;
  int v = (i < NNODES) ? data[i] : 0;
  tmp[threadIdx.x] = v;
  __syncthreads();
  for (int off = 1; off < 256; off <<= 1) {
    int t = (threadIdx.x >= off) ? tmp[threadIdx.x - off] : 0;
    __syncthreads();
    tmp[threadIdx.x] += t;
    __syncthreads();
  }
  if (i < NNODES) data[i] = tmp[threadIdx.x] - v;   // exclusive
  if (threadIdx.x == 255) bsum[blockIdx.x] = tmp[255];
}

__global__ void k_scan2(int* __restrict__ bsum, int* __restrict__ bex) {
  __shared__ int tmp[512];
  int v = (threadIdx.x < NBLK) ? bsum[threadIdx.x] : 0;
  tmp[threadIdx.x] = v;
  __syncthreads();
  for (int off = 1; off < 512; off <<= 1) {
    int t = (threadIdx.x >= off) ? tmp[threadIdx.x - off] : 0;
    __syncthreads();
    tmp[threadIdx.x] += t;
    __syncthreads();
  }
  if (threadIdx.x < NBLK) bex[threadIdx.x] = tmp[threadIdx.x] - v;
}

__global__ void k_scan3(int* __restrict__ data, const int* __restrict__ bex) {
  int i = blockIdx.x * 256 + threadIdx.x;
  if (i < NNODES) data[i] += bex[blockIdx.x];
  if (i == 0) data[NNODES] = NEDGE;
}

// fill both CSRs: dst list stores (src, e) packed; src list stores e
__global__ void k_fill2(const int* __restrict__ ei, const int* __restrict__ rowptrD,
                        const int* __restrict__ rowptrS, int* __restrict__ fcD,
                        int* __restrict__ fcS, int2* __restrict__ eD,
                        int* __restrict__ eS) {
  int e = blockIdx.x * blockDim.x + threadIdx.x;
  if (e >= NEDGE) return;
  int s = ei[e];
  int d = ei[NEDGE + e];
  int posD = rowptrD[d] + atomicAdd(&fcD[d], 1);
  eD[posD] = make_int2(s, e);
  int posS = rowptrS[s] + atomicAdd(&fcS[s], 1);
  eS[posS] = e;
}

// ---------- layer-1 GEMM (K=8): W1 in registers ----------
__global__ void k_gemm_in(const float* __restrict__ x, const float* __restrict__ W,
                          float* __restrict__ h) {
  int tid = blockIdx.x * blockDim.x + threadIdx.x;
  int tx = tid & 15;
  int c0 = tx * 8;
  float4 wv[16];
#pragma unroll
  for (int j = 0; j < 8; j++) {
    wv[j * 2 + 0] = *(const float4*)(W + (size_t)(c0 + j) * IN_DIM);
    wv[j * 2 + 1] = *(const float4*)(W + (size_t)(c0 + j) * IN_DIM + 4);
  }
  int stride = (gridDim.x * blockDim.x) >> 4;
  for (int n = tid >> 4; n < NNODES; n += stride) {
    float4 x0 = *(const float4*)(x + (size_t)n * IN_DIM);
    float4 x1 = *(const float4*)(x + (size_t)n * IN_DIM + 4);
    float o[8];
#pragma unroll
    for (int j = 0; j < 8; j++) {
      float4 a = wv[j * 2], b = wv[j * 2 + 1];
      o[j] = x0.x*a.x + x0.y*a.y + x0.z*a.z + x0.w*a.w
           + x1.x*b.x + x1.y*b.y + x1.z*b.z + x1.w*b.w;
    }
    float4* hp = (float4*)(h + (size_t)n * HID + c0);
    hp[0] = make_float4(o[0], o[1], o[2], o[3]);
    hp[1] = make_float4(o[4], o[5], o[6], o[7]);
  }
}

// ---------- 128x128 GEMM: 8x8 per thread, W^T in LDS ----------
#define GB_NODES 128
__global__ __launch_bounds__(256, 2)
void k_gemm128_t(const float* __restrict__ x, const float* __restrict__ W,
                 float* __restrict__ h) {
  __shared__ float sw[HID][HID + 4];
  int tid = threadIdx.x;
  for (int idx = tid * 4; idx < HID * HID; idx += 256 * 4) {
    int c = idx >> 7, k = idx & 127;
    float4 w = *(const float4*)(W + (size_t)c * HID + k);
    sw[k + 0][c] = w.x; sw[k + 1][c] = w.y; sw[k + 2][c] = w.z; sw[k + 3][c] = w.w;
  }
  __syncthreads();
  int tx = tid & 15, ty = tid >> 4;
  int n0 = blockIdx.x * GB_NODES + ty * 8;
  int c0 = tx * 8;
  float acc[8][8];
#pragma unroll
  for (int i = 0; i < 8; i++)
#pragma unroll
    for (int j = 0; j < 8; j++) acc[i][j] = 0.f;

  const float* xp = x + (size_t)n0 * HID;
  for (int kk = 0; kk < HID; kk += 4) {
    float4 xv[8];
#pragma unroll
    for (int i = 0; i < 8; i++) xv[i] = *(const float4*)(xp + (size_t)i * HID + kk);
#pragma unroll
    for (int k4 = 0; k4 < 4; k4++) {
      float4 w0 = *(const float4*)&sw[kk + k4][c0];
      float4 w1 = *(const float4*)&sw[kk + k4][c0 + 4];
      float wj[8] = { w0.x, w0.y, w0.z, w0.w, w1.x, w1.y, w1.z, w1.w };
#pragma unroll
      for (int i = 0; i < 8; i++) {
        const float* xe = (const float*)&xv[i];
        float xs = xe[k4];
#pragma unroll
        for (int j = 0; j < 8; j++) acc[i][j] += xs * wj[j];
      }
    }
  }
#pragma unroll
  for (int i = 0; i < 8; i++) {
    float4* hp = (float4*)(h + (size_t)(n0 + i) * HID + c0);
    hp[0] = make_float4(acc[i][0], acc[i][1], acc[i][2], acc[i][3]);
    hp[1] = make_float4(acc[i][4], acc[i][5], acc[i][6], acc[i][7]);
  }
}

__global__ void k_att_node(const float* __restrict__ h, const float* __restrict__ att,
                           float* __restrict__ aL, float* __restrict__ aR) {
  __shared__ float satt[HEADS * 2 * KH];
  for (int i = threadIdx.x; i < HEADS * 2 * KH; i += blockDim.x) satt[i] = att[i];
  __syncthreads();
  int total = NNODES * HEADS;
  for (int idx = blockIdx.x * blockDim.x + threadIdx.x; idx < total;
       idx += gridDim.x * blockDim.x) {
    int n = idx >> 3, hd = idx & 7;
    const float* hp  = h + (size_t)n * HID + hd * KH;
    const float* aLw = satt + hd * 2 * KH;
    const float* aRw = aLw + KH;
    float sl = 0.f, sr = 0.f;
#pragma unroll
    for (int c = 0; c < KH; c++) { float v = hp[c]; sl += v * aLw[c]; sr += v * aRw[c]; }
    aL[idx] = sl; aR[idx] = sr;
  }
}

// per real edge: a = lrelu(aL[dst] + aR[src]), stored to ae (no atomics)
__global__ void k_edge_a(const int* __restrict__ ei, const float* __restrict__ aL,
                         const float* __restrict__ aR, float* __restrict__ ae) {
  int e = blockIdx.x * blockDim.x + threadIdx.x;
  if (e >= NEDGE) return;
  int s = ei[e], d = ei[NEDGE + e];
  float4 l0 = *(const float4*)(aL + (size_t)d * 8);
  float4 l1 = *(const float4*)(aL + (size_t)d * 8 + 4);
  float4 r0 = *(const float4*)(aR + (size_t)s * 8);
  float4 r1 = *(const float4*)(aR + (size_t)s * 8 + 4);
  float4 a0 = make_float4(lrelu(l0.x + r0.x), lrelu(l0.y + r0.y),
                          lrelu(l0.z + r0.z), lrelu(l0.w + r0.w));
  float4 a1 = make_float4(lrelu(l1.x + r1.x), lrelu(l1.y + r1.y),
                          lrelu(l1.z + r1.z), lrelu(l1.w + r1.w));
  float4* ap = (float4*)(ae + (size_t)e * 8);
  ap[0] = a0; ap[1] = a1;
}

// per (node, head): online softmax over out-edges (src-CSR) + self-loop;
// writes alpha in place into ae and self-alpha into aself. No atomics.
__global__ void k_src_softmax(const int* __restrict__ rowptrS, const int* __restrict__ eS,
                              const float* __restrict__ aL, const float* __restrict__ aR,
                              float* __restrict__ ae, float* __restrict__ aself) {
  int t = blockIdx.x * blockDim.x + threadIdx.x;
  int n = t >> 3;
  if (n >= NNODES) return;
  int hd = t & 7;
  int sh = n * 8 + hd;
  float aself_a = lrelu(aL[sh] + aR[sh]);
  float m = aself_a, l = 1.f;
  int j0 = rowptrS[n], j1 = rowptrS[n + 1];
  for (int j = j0; j < j1; j++) {
    int e = eS[j];
    float a = ae[(size_t)e * 8 + hd];
    if (a > m) { l = l * __expf(m - a) + 1.f; m = a; }
    else       { l += __expf(a - m); }
  }
  float rinv = 1.f / (l + 1e-16f);
  aself[sh] = __expf(aself_a - m) * rinv;
  for (int j = j0; j < j1; j++) {
    int e = eS[j];
    size_t idx = (size_t)e * 8 + hd;
    ae[idx] = __expf(ae[idx] - m) * rinv;
  }
}

// gather aggregation via dst-CSR; fuse bias+relu
__global__ __launch_bounds__(256)
void k_agg_gather(const int* __restrict__ rowptrD, const int2* __restrict__ eD,
                  const float* __restrict__ ae, const float* __restrict__ aself,
                  const float* __restrict__ h, const float* __restrict__ bias,
                  float* __restrict__ yout) {
  int node = blockIdx.x * 2 + (threadIdx.x >> 7);
  if (node >= NNODES) return;
  int c = threadIdx.x & 127;
  int hd = c >> 4;
  float acc = aself[node * 8 + hd] * h[(size_t)node * HID + c];
  int j = rowptrD[node], j1 = rowptrD[node + 1];
  for (; j + 1 < j1; j += 2) {
    int2 p0 = eD[j], p1 = eD[j + 1];
    float al0 = ae[(size_t)p0.y * 8 + hd];
    float al1 = ae[(size_t)p1.y * 8 + hd];
    float h0 = h[(size_t)p0.x * HID + c];
    float h1 = h[(size_t)p1.x * HID + c];
    acc += al0 * h0 + al1 * h1;
  }
  if (j < j1) {
    int2 p0 = eD[j];
    acc += ae[(size_t)p0.y * 8 + hd] * h[(size_t)p0.x * HID + c];
  }
  float v = acc + bias[c];
  yout[(size_t)node * HID + c] = v > 0.f ? v : 0.f;
}

// BN statistics (read-only over y)
__global__ void k_bnstats(const float* __restrict__ y, double* __restrict__ bnsum,
                          double* __restrict__ bnsq) {
  int c = threadIdx.x;
  float s = 0.f, sq = 0.f;
  for (int n = blockIdx.x; n < NNODES; n += gridDim.x) {
    float v = y[(size_t)n * HID + c];
    s += v; sq += v * v;
  }
  atomicAdd(&bnsum[c], (double)s);
  atomicAdd(&bnsq[c], (double)sq);
}

__global__ void k_bnfinal(const double* __restrict__ bnsum, const double* __restrict__ bnsq,
                          const float* __restrict__ g, const float* __restrict__ be,
                          float* __restrict__ scale, float* __restrict__ shift) {
  int c = threadIdx.x;
  double mean = bnsum[c] / (double)NNODES;
  double var  = bnsq[c] / (double)NNODES - mean * mean;
  float rs = (float)(1.0 / sqrt(var + (double)EPSBN));
  float sc = g[c] * rs;
  scale[c] = sc;
  shift[c] = be[c] - (float)mean * sc;
}

__global__ void k_bnapply(const float* __restrict__ y, const float* __restrict__ scale,
                          const float* __restrict__ shift, float* __restrict__ xo) {
  int total = NNODES * HID;
  for (int idx = blockIdx.x * blockDim.x + threadIdx.x; idx < total;
       idx += gridDim.x * blockDim.x) {
    int c = idx & 127;
    xo[idx] = lrelu(y[idx] * scale[c] + shift[c]);
  }
}

__global__ void k_pmean(const float* __restrict__ xf, const float* __restrict__ p_,
                        float* __restrict__ xgsum) {
  int b = blockIdx.y, c = threadIdx.x;
  float p = p_[0];
  int rows_per = (PERB + gridDim.x - 1) / gridDim.x;
  int r0 = blockIdx.x * rows_per;
  int r1 = r0 + rows_per; if (r1 > PERB) r1 = PERB;
  float acc = 0.f;
  for (int i = r0; i < r1; i++) {
    float v = xf[((size_t)b * PERB + i) * HID + c];
    v = fminf(fmaxf(v, 0.f), 100.f);
    acc += powf(v, p);
  }
  atomicAdd(&xgsum[b * HID + c], acc);
}

__global__ void k_head(const float* __restrict__ xgsum, const float* __restrict__ p_,
                       const float* __restrict__ Wg, const float* __restrict__ bg,
                       float* __restrict__ out) {
  __shared__ float sxg[HID];
  __shared__ float red[HID];
  int b = blockIdx.x, c = threadIdx.x;
  float p = p_[0];
  float m = xgsum[b * HID + c] / (float)PERB;
  m = fminf(fmaxf(m, 0.f), 100.f);
  sxg[c] = powf(m, 1.0f / p);
  __syncthreads();
  float l0 = 0.f, l1 = 0.f;
  for (int j = 0; j < 2; j++) {
    red[c] = sxg[c] * Wg[j * HID + c];
    __syncthreads();
    for (int off = 64; off > 0; off >>= 1) {
      if (c < off) red[c] += red[c + off];
      __syncthreads();
    }
    if (c == 0) { if (j == 0) l0 = red[0] + bg[0]; else l1 = red[0] + bg[1]; }
    __syncthreads();
  }
  if (c == 0) {
    out[b * 2 + 0] = l0;
    out[b * 2 + 1] = l1;
    out[2 * BATCH + b] = (l1 > l0) ? 1.0f : 0.0f;
  }
}

extern "C" void kernel_launch(void* const* d_in, const int* in_sizes, int n_in,
                              void* d_out, int out_size, void* d_ws, size_t ws_size,
                              hipStream_t stream) {
  (void)in_sizes; (void)n_in; (void)out_size; (void)ws_size;
  const float* x    = (const float*)d_in[0];
  const int*   ei   = (const int*)d_in[1];
  const float* Wl[3]   = { (const float*)d_in[2],  (const float*)d_in[7],  (const float*)d_in[12] };
  const float* attl[3] = { (const float*)d_in[3],  (const float*)d_in[8],  (const float*)d_in[13] };
  const float* bl[3]   = { (const float*)d_in[4],  (const float*)d_in[9],  (const float*)d_in[14] };
  const float* gl[3]   = { (const float*)d_in[5],  (const float*)d_in[10], (const float*)d_in[15] };
  const float* bel[3]  = { (const float*)d_in[6],  (const float*)d_in[11], (const float*)d_in[16] };
  const float* p    = (const float*)d_in[17];
  const float* Wg   = (const float*)d_in[18];
  const float* bg   = (const float*)d_in[19];
  float* out = (float*)d_out;

  float* ws   = (float*)d_ws;
  float* h    = ws;                                  // N*128
  float* agg  = h    + (size_t)NNODES * HID;         // N*128 (= y)
  float* xbuf = agg  + (size_t)NNODES * HID;         // N*128 (aliased as ae during edge phase)
  float* aL   = xbuf + (size_t)NNODES * HID;         // N*8
  float* aR   = aL   + (size_t)NNODES * HEADS;
  float* aself= aR   + (size_t)NNODES * HEADS;       // N*8
  double* bnsum = (double*)(aself + (size_t)NNODES * HEADS);
  double* bnsq  = bnsum + HID;
  float* scale  = (float*)(bnsq + HID);
  float* shift  = scale + HID;
  float* xgsum  = shift + HID;                       // 8*128
  // CSR scratch (after xgsum; float offset is even -> 8B aligned for int2)
  int2* eD      = (int2*)(xgsum + BATCH * HID);      // NEDGE pairs (src, e)
  int*  eS      = (int*)(eD + NEDGE);                // NEDGE
  int* rowptrD  = eS + NEDGE;                        // N+1
  int* rowptrS  = rowptrD + (NNODES + 1);            // N+1
  int* fcD      = rowptrS + (NNODES + 1);            // N
  int* fcS      = fcD + NNODES;                      // N
  int* bsum     = fcS + NNODES;                      // NBLK
  int* bex      = bsum + NBLK;                       // NBLK
  float* ae = xbuf;                                  // NEDGE*8 == N*128 exactly

  // ---- build dst-CSR and src-CSR ----
  hipMemsetAsync(rowptrD, 0, sizeof(int) * (4 * NNODES + 2), stream);
  k_count2<<<(NEDGE + 255) / 256, 256, 0, stream>>>(ei, rowptrD, rowptrS);
  k_scan1<<<NBLK, 256, 0, stream>>>(rowptrD, bsum);
  k_scan2<<<1, 512, 0, stream>>>(bsum, bex);
  k_scan3<<<NBLK, 256, 0, stream>>>(rowptrD, bex);
  k_scan1<<<NBLK, 256, 0, stream>>>(rowptrS, bsum);
  k_scan2<<<1, 512, 0, stream>>>(bsum, bex);
  k_scan3<<<NBLK, 256, 0, stream>>>(rowptrS, bex);
  k_fill2<<<(NEDGE + 255) / 256, 256, 0, stream>>>(ei, rowptrD, rowptrS, fcD, fcS, eD, eS);

  for (int layer = 0; layer < 3; layer++) {
    const float* xin = (layer == 0) ? x : xbuf;
    if (layer == 0) k_gemm_in<<<2048, 256, 0, stream>>>(xin, Wl[0], h);
    else            k_gemm128_t<<<NNODES / GB_NODES, 256, 0, stream>>>(xin, Wl[layer], h);

    k_att_node<<<2500, 256, 0, stream>>>(h, attl[layer], aL, aR);

    k_edge_a<<<(NEDGE + 255) / 256, 256, 0, stream>>>(ei, aL, aR, ae);
    k_src_softmax<<<(NNODES * 8 + 255) / 256, 256, 0, stream>>>(rowptrS, eS, aL, aR, ae, aself);
    k_agg_gather<<<NNODES / 2, 256, 0, stream>>>(rowptrD, eD, ae, aself, h, bl[layer], agg);

    hipMemsetAsync(bnsum, 0, sizeof(double) * HID * 2, stream);
    k_bnstats<<<1024, 128, 0, stream>>>(agg, bnsum, bnsq);
    k_bnfinal<<<1, 128, 0, stream>>>(bnsum, bnsq, gl[layer], bel[layer], scale, shift);
    k_bnapply<<<4096, 256, 0, stream>>>(agg, scale, shift, xbuf);
  }

  hipMemsetAsync(xgsum, 0, sizeof(float) * BATCH * HID, stream);
  k_pmean<<<dim3(32, BATCH), 128, 0, stream>>>(xbuf, p, xgsum);
  k_head<<<BATCH, 128, 0, stream>>>(xgsum, p, Wg, bg, out);
}

// Round 8
// 1537.605 us; speedup vs baseline: 3.0820x; 1.1277x over previous
//
#include <hip/hip_runtime.h>
#include <math.h>

#define NNODES   80000
#define IN_DIM   8
#define HID      128
#define HEADS    8
#define KH       16
#define NEDGE    1280000
#define NETOT    (NEDGE + NNODES)
#define NEGS     0.2f
#define EPSBN    1e-5f
#define BATCH    8
#define PERB     10000
#define NBLK     313            // ceil(80000/256)

__device__ __forceinline__ float lrelu(float v) { return v >= 0.f ? v : NEGS * v; }

// ---------- CSR build (dst and src), once per call ----------
__global__ void k_count2(const int* __restrict__ ei, int* __restrict__ cntD,
                         int* __restrict__ cntS) {
  int e = blockIdx.x * blockDim.x + threadIdx.x;
  if (e >= NEDGE) return;
  atomicAdd(&cntD[ei[NEDGE + e]], 1);
  atomicAdd(&cntS[ei[e]], 1);
}

// in-place exclusive scan, stage 1: per-block scan + block sums
__global__ void k_scan1(int* __restrict__ data, int* __restrict__ bsum) {
  __shared__ int tmp[256];
  int i = blockIdx.x * 256 + threadIdx.x;
  int v = (i < NNODES) ? data[i] : 0;
  tmp[threadIdx.x] = v;
  __syncthreads();
  for (int off = 1; off < 256; off <<= 1) {
    int t = (threadIdx.x >= off) ? tmp[threadIdx.x - off] : 0;
    __syncthreads();
    tmp[threadIdx.x] += t;
    __syncthreads();
  }
  if (i < NNODES) data[i] = tmp[threadIdx.x] - v;   // exclusive
  if (threadIdx.x == 255) bsum[blockIdx.x] = tmp[255];
}

__global__ void k_scan2(int* __restrict__ bsum, int* __restrict__ bex) {
  __shared__ int tmp[512];
  int v = (threadIdx.x < NBLK) ? bsum[threadIdx.x] : 0;
  tmp[threadIdx.x] = v;
  __syncthreads();
  for (int off = 1; off < 512; off <<= 1) {
    int t = (threadIdx.x >= off) ? tmp[threadIdx.x - off] : 0;
    __syncthreads();
    tmp[threadIdx.x] += t;
    __syncthreads();
  }
  if (threadIdx.x < NBLK) bex[threadIdx.x] = tmp[threadIdx.x] - v;
}

__global__ void k_scan3(int* __restrict__ data, const int* __restrict__ bex) {
  int i = blockIdx.x * 256 + threadIdx.x;
  if (i < NNODES) data[i] += bex[blockIdx.x];
  if (i == 0) data[NNODES] = NEDGE;
}

// fill both CSRs:
//   src list stores the edge's DST node (for on-the-fly a computation)
//   dst list stores (src, posS) where posS = position in src-CSR order
//   -> alpha will live in src-CSR order, indexed directly by the gather
__global__ void k_fill2(const int* __restrict__ ei, const int* __restrict__ rowptrD,
                        const int* __restrict__ rowptrS, int* __restrict__ fcD,
                        int* __restrict__ fcS, int2* __restrict__ eD,
                        int* __restrict__ eSd) {
  int e = blockIdx.x * blockDim.x + threadIdx.x;
  if (e >= NEDGE) return;
  int s = ei[e];
  int d = ei[NEDGE + e];
  int posS = rowptrS[s] + atomicAdd(&fcS[s], 1);
  eSd[posS] = d;
  int posD = rowptrD[d] + atomicAdd(&fcD[d], 1);
  eD[posD] = make_int2(s, posS);
}

// ---------- layer-1 GEMM (K=8): W1 in registers ----------
__global__ void k_gemm_in(const float* __restrict__ x, const float* __restrict__ W,
                          float* __restrict__ h) {
  int tid = blockIdx.x * blockDim.x + threadIdx.x;
  int tx = tid & 15;
  int c0 = tx * 8;
  float4 wv[16];
#pragma unroll
  for (int j = 0; j < 8; j++) {
    wv[j * 2 + 0] = *(const float4*)(W + (size_t)(c0 + j) * IN_DIM);
    wv[j * 2 + 1] = *(const float4*)(W + (size_t)(c0 + j) * IN_DIM + 4);
  }
  int stride = (gridDim.x * blockDim.x) >> 4;
  for (int n = tid >> 4; n < NNODES; n += stride) {
    float4 x0 = *(const float4*)(x + (size_t)n * IN_DIM);
    float4 x1 = *(const float4*)(x + (size_t)n * IN_DIM + 4);
    float o[8];
#pragma unroll
    for (int j = 0; j < 8; j++) {
      float4 a = wv[j * 2], b = wv[j * 2 + 1];
      o[j] = x0.x*a.x + x0.y*a.y + x0.z*a.z + x0.w*a.w
           + x1.x*b.x + x1.y*b.y + x1.z*b.z + x1.w*b.w;
    }
    float4* hp = (float4*)(h + (size_t)n * HID + c0);
    hp[0] = make_float4(o[0], o[1], o[2], o[3]);
    hp[1] = make_float4(o[4], o[5], o[6], o[7]);
  }
}

// ---------- 128x128 GEMM: 8x8 per thread, W^T in LDS ----------
#define GB_NODES 128
__global__ __launch_bounds__(256, 2)
void k_gemm128_t(const float* __restrict__ x, const float* __restrict__ W,
                 float* __restrict__ h) {
  __shared__ float sw[HID][HID + 4];
  int tid = threadIdx.x;
  for (int idx = tid * 4; idx < HID * HID; idx += 256 * 4) {
    int c = idx >> 7, k = idx & 127;
    float4 w = *(const float4*)(W + (size_t)c * HID + k);
    sw[k + 0][c] = w.x; sw[k + 1][c] = w.y; sw[k + 2][c] = w.z; sw[k + 3][c] = w.w;
  }
  __syncthreads();
  int tx = tid & 15, ty = tid >> 4;
  int n0 = blockIdx.x * GB_NODES + ty * 8;
  int c0 = tx * 8;
  float acc[8][8];
#pragma unroll
  for (int i = 0; i < 8; i++)
#pragma unroll
    for (int j = 0; j < 8; j++) acc[i][j] = 0.f;

  const float* xp = x + (size_t)n0 * HID;
  for (int kk = 0; kk < HID; kk += 4) {
    float4 xv[8];
#pragma unroll
    for (int i = 0; i < 8; i++) xv[i] = *(const float4*)(xp + (size_t)i * HID + kk);
#pragma unroll
    for (int k4 = 0; k4 < 4; k4++) {
      float4 w0 = *(const float4*)&sw[kk + k4][c0];
      float4 w1 = *(const float4*)&sw[kk + k4][c0 + 4];
      float wj[8] = { w0.x, w0.y, w0.z, w0.w, w1.x, w1.y, w1.z, w1.w };
#pragma unroll
      for (int i = 0; i < 8; i++) {
        const float* xe = (const float*)&xv[i];
        float xs = xe[k4];
#pragma unroll
        for (int j = 0; j < 8; j++) acc[i][j] += xs * wj[j];
      }
    }
  }
#pragma unroll
  for (int i = 0; i < 8; i++) {
    float4* hp = (float4*)(h + (size_t)(n0 + i) * HID + c0);
    hp[0] = make_float4(acc[i][0], acc[i][1], acc[i][2], acc[i][3]);
    hp[1] = make_float4(acc[i][4], acc[i][5], acc[i][6], acc[i][7]);
  }
}

__global__ void k_att_node(const float* __restrict__ h, const float* __restrict__ att,
                           float* __restrict__ aL, float* __restrict__ aR) {
  __shared__ float satt[HEADS * 2 * KH];
  for (int i = threadIdx.x; i < HEADS * 2 * KH; i += blockDim.x) satt[i] = att[i];
  __syncthreads();
  int total = NNODES * HEADS;
  for (int idx = blockIdx.x * blockDim.x + threadIdx.x; idx < total;
       idx += gridDim.x * blockDim.x) {
    int n = idx >> 3, hd = idx & 7;
    const float* hp  = h + (size_t)n * HID + hd * KH;
    const float* aLw = satt + hd * 2 * KH;
    const float* aRw = aLw + KH;
    float sl = 0.f, sr = 0.f;
#pragma unroll
    for (int c = 0; c < KH; c++) { float v = hp[c]; sl += v * aLw[c]; sr += v * aRw[c]; }
    aL[idx] = sl; aR[idx] = sr;
  }
}

// per (node, head): online softmax over out-edges, computing a on the fly
// from aL[dst] (L2-resident gather). alpha written in src-CSR order
// (sequential). No atomics, no per-edge scattered reads.
__global__ void k_src_softmax(const int* __restrict__ rowptrS, const int* __restrict__ eSd,
                              const float* __restrict__ aL, const float* __restrict__ aR,
                              float* __restrict__ alphaS, float* __restrict__ aself) {
  int t = blockIdx.x * blockDim.x + threadIdx.x;
  int n = t >> 3;
  if (n >= NNODES) return;
  int hd = t & 7;
  int sh = n * 8 + hd;
  float aRn = aR[sh];
  float aself_a = lrelu(aL[sh] + aRn);
  float m = aself_a, l = 1.f;
  int j0 = rowptrS[n], j1 = rowptrS[n + 1];
  for (int j = j0; j < j1; j++) {
    int d = eSd[j];
    float a = lrelu(aL[d * 8 + hd] + aRn);
    alphaS[(size_t)j * 8 + hd] = a;         // sequential (32B per edge per 8-lane group)
    if (a > m) { l = l * __expf(m - a) + 1.f; m = a; }
    else       { l += __expf(a - m); }
  }
  float rinv = 1.f / (l + 1e-16f);
  aself[sh] = __expf(aself_a - m) * rinv;
  for (int j = j0; j < j1; j++) {
    size_t idx = (size_t)j * 8 + hd;
    alphaS[idx] = __expf(alphaS[idx] - m) * rinv;   // L2-hot re-read, sequential
  }
}

// gather aggregation via dst-CSR; fuse bias+relu
__global__ __launch_bounds__(256)
void k_agg_gather(const int* __restrict__ rowptrD, const int2* __restrict__ eD,
                  const float* __restrict__ alphaS, const float* __restrict__ aself,
                  const float* __restrict__ h, const float* __restrict__ bias,
                  float* __restrict__ yout) {
  int node = blockIdx.x * 2 + (threadIdx.x >> 7);
  if (node >= NNODES) return;
  int c = threadIdx.x & 127;
  int hd = c >> 4;
  float acc = aself[node * 8 + hd] * h[(size_t)node * HID + c];
  int j = rowptrD[node], j1 = rowptrD[node + 1];
  for (; j + 1 < j1; j += 2) {
    int2 p0 = eD[j], p1 = eD[j + 1];
    float al0 = alphaS[(size_t)p0.y * 8 + hd];
    float al1 = alphaS[(size_t)p1.y * 8 + hd];
    float h0 = h[(size_t)p0.x * HID + c];
    float h1 = h[(size_t)p1.x * HID + c];
    acc += al0 * h0 + al1 * h1;
  }
  if (j < j1) {
    int2 p0 = eD[j];
    acc += alphaS[(size_t)p0.y * 8 + hd] * h[(size_t)p0.x * HID + c];
  }
  float v = acc + bias[c];
  yout[(size_t)node * HID + c] = v > 0.f ? v : 0.f;
}

// BN statistics (read-only over y)
__global__ void k_bnstats(const float* __restrict__ y, double* __restrict__ bnsum,
                          double* __restrict__ bnsq) {
  int c = threadIdx.x;
  float s = 0.f, sq = 0.f;
  for (int n = blockIdx.x; n < NNODES; n += gridDim.x) {
    float v = y[(size_t)n * HID + c];
    s += v; sq += v * v;
  }
  atomicAdd(&bnsum[c], (double)s);
  atomicAdd(&bnsq[c], (double)sq);
}

__global__ void k_bnfinal(const double* __restrict__ bnsum, const double* __restrict__ bnsq,
                          const float* __restrict__ g, const float* __restrict__ be,
                          float* __restrict__ scale, float* __restrict__ shift) {
  int c = threadIdx.x;
  double mean = bnsum[c] / (double)NNODES;
  double var  = bnsq[c] / (double)NNODES - mean * mean;
  float rs = (float)(1.0 / sqrt(var + (double)EPSBN));
  float sc = g[c] * rs;
  scale[c] = sc;
  shift[c] = be[c] - (float)mean * sc;
}

__global__ void k_bnapply(const float* __restrict__ y, const float* __restrict__ scale,
                          const float* __restrict__ shift, float* __restrict__ xo) {
  int total = NNODES * HID;
  for (int idx = blockIdx.x * blockDim.x + threadIdx.x; idx < total;
       idx += gridDim.x * blockDim.x) {
    int c = idx & 127;
    xo[idx] = lrelu(y[idx] * scale[c] + shift[c]);
  }
}

__global__ void k_pmean(const float* __restrict__ xf, const float* __restrict__ p_,
                        float* __restrict__ xgsum) {
  int b = blockIdx.y, c = threadIdx.x;
  float p = p_[0];
  int rows_per = (PERB + gridDim.x - 1) / gridDim.x;
  int r0 = blockIdx.x * rows_per;
  int r1 = r0 + rows_per; if (r1 > PERB) r1 = PERB;
  float acc = 0.f;
  for (int i = r0; i < r1; i++) {
    float v = xf[((size_t)b * PERB + i) * HID + c];
    v = fminf(fmaxf(v, 0.f), 100.f);
    acc += powf(v, p);
  }
  atomicAdd(&xgsum[b * HID + c], acc);
}

__global__ void k_head(const float* __restrict__ xgsum, const float* __restrict__ p_,
                       const float* __restrict__ Wg, const float* __restrict__ bg,
                       float* __restrict__ out) {
  __shared__ float sxg[HID];
  __shared__ float red[HID];
  int b = blockIdx.x, c = threadIdx.x;
  float p = p_[0];
  float m = xgsum[b * HID + c] / (float)PERB;
  m = fminf(fmaxf(m, 0.f), 100.f);
  sxg[c] = powf(m, 1.0f / p);
  __syncthreads();
  float l0 = 0.f, l1 = 0.f;
  for (int j = 0; j < 2; j++) {
    red[c] = sxg[c] * Wg[j * HID + c];
    __syncthreads();
    for (int off = 64; off > 0; off >>= 1) {
      if (c < off) red[c] += red[c + off];
      __syncthreads();
    }
    if (c == 0) { if (j == 0) l0 = red[0] + bg[0]; else l1 = red[0] + bg[1]; }
    __syncthreads();
  }
  if (c == 0) {
    out[b * 2 + 0] = l0;
    out[b * 2 + 1] = l1;
    out[2 * BATCH + b] = (l1 > l0) ? 1.0f : 0.0f;
  }
}

extern "C" void kernel_launch(void* const* d_in, const int* in_sizes, int n_in,
                              void* d_out, int out_size, void* d_ws, size_t ws_size,
                              hipStream_t stream) {
  (void)in_sizes; (void)n_in; (void)out_size; (void)ws_size;
  const float* x    = (const float*)d_in[0];
  const int*   ei   = (const int*)d_in[1];
  const float* Wl[3]   = { (const float*)d_in[2],  (const float*)d_in[7],  (const float*)d_in[12] };
  const float* attl[3] = { (const float*)d_in[3],  (const float*)d_in[8],  (const float*)d_in[13] };
  const float* bl[3]   = { (const float*)d_in[4],  (const float*)d_in[9],  (const float*)d_in[14] };
  const float* gl[3]   = { (const float*)d_in[5],  (const float*)d_in[10], (const float*)d_in[15] };
  const float* bel[3]  = { (const float*)d_in[6],  (const float*)d_in[11], (const float*)d_in[16] };
  const float* p    = (const float*)d_in[17];
  const float* Wg   = (const float*)d_in[18];
  const float* bg   = (const float*)d_in[19];
  float* out = (float*)d_out;

  float* ws   = (float*)d_ws;
  float* h    = ws;                                  // N*128
  float* agg  = h    + (size_t)NNODES * HID;         // N*128 (= y)
  float* xbuf = agg  + (size_t)NNODES * HID;         // N*128 (aliased as alphaS during edge phase)
  float* aL   = xbuf + (size_t)NNODES * HID;         // N*8
  float* aR   = aL   + (size_t)NNODES * HEADS;
  float* aself= aR   + (size_t)NNODES * HEADS;       // N*8
  double* bnsum = (double*)(aself + (size_t)NNODES * HEADS);
  double* bnsq  = bnsum + HID;
  float* scale  = (float*)(bnsq + HID);
  float* shift  = scale + HID;
  float* xgsum  = shift + HID;                       // 8*128
  // CSR scratch (after xgsum; float offset is even -> 8B aligned for int2)
  int2* eD      = (int2*)(xgsum + BATCH * HID);      // NEDGE pairs (src, posS)
  int*  eSd     = (int*)(eD + NEDGE);                // NEDGE (dst per src-ordered edge)
  int* rowptrD  = eSd + NEDGE;                       // N+1
  int* rowptrS  = rowptrD + (NNODES + 1);            // N+1
  int* fcD      = rowptrS + (NNODES + 1);            // N
  int* fcS      = fcD + NNODES;                      // N
  int* bsum     = fcS + NNODES;                      // NBLK
  int* bex      = bsum + NBLK;                       // NBLK
  float* alphaS = xbuf;                              // NEDGE*8 == N*128 exactly

  // ---- build dst-CSR and src-CSR ----
  hipMemsetAsync(rowptrD, 0, sizeof(int) * (4 * NNODES + 2), stream);
  k_count2<<<(NEDGE + 255) / 256, 256, 0, stream>>>(ei, rowptrD, rowptrS);
  k_scan1<<<NBLK, 256, 0, stream>>>(rowptrD, bsum);
  k_scan2<<<1, 512, 0, stream>>>(bsum, bex);
  k_scan3<<<NBLK, 256, 0, stream>>>(rowptrD, bex);
  k_scan1<<<NBLK, 256, 0, stream>>>(rowptrS, bsum);
  k_scan2<<<1, 512, 0, stream>>>(bsum, bex);
  k_scan3<<<NBLK, 256, 0, stream>>>(rowptrS, bex);
  k_fill2<<<(NEDGE + 255) / 256, 256, 0, stream>>>(ei, rowptrD, rowptrS, fcD, fcS, eD, eSd);

  for (int layer = 0; layer < 3; layer++) {
    const float* xin = (layer == 0) ? x : xbuf;
    if (layer == 0) k_gemm_in<<<2048, 256, 0, stream>>>(xin, Wl[0], h);
    else            k_gemm128_t<<<NNODES / GB_NODES, 256, 0, stream>>>(xin, Wl[layer], h);

    k_att_node<<<2500, 256, 0, stream>>>(h, attl[layer], aL, aR);

    k_src_softmax<<<(NNODES * 8 + 255) / 256, 256, 0, stream>>>(rowptrS, eSd, aL, aR, alphaS, aself);
    k_agg_gather<<<NNODES / 2, 256, 0, stream>>>(rowptrD, eD, alphaS, aself, h, bl[layer], agg);

    hipMemsetAsync(bnsum, 0, sizeof(double) * HID * 2, stream);
    k_bnstats<<<1024, 128, 0, stream>>>(agg, bnsum, bnsq);
    k_bnfinal<<<1, 128, 0, stream>>>(bnsum, bnsq, gl[layer], bel[layer], scale, shift);
    k_bnapply<<<4096, 256, 0, stream>>>(agg, scale, shift, xbuf);
  }

  hipMemsetAsync(xgsum, 0, sizeof(float) * BATCH * HID, stream);
  k_pmean<<<dim3(32, BATCH), 128, 0, stream>>>(xbuf, p, xgsum);
  k_head<<<BATCH, 128, 0, stream>>>(xgsum, p, Wg, bg, out);
}

// Round 9
// 1425.200 us; speedup vs baseline: 3.3250x; 1.0789x over previous
//
#include <hip/hip_runtime.h>
#include <math.h>

#define NNODES   80000
#define IN_DIM   8
#define HID      128
#define HEADS    8
#define KH       16
#define NEDGE    1280000
#define NETOT    (NEDGE + NNODES)
#define NEGS     0.2f
#define EPSBN    1e-5f
#define BATCH    8
#define PERB     10000
#define NBLK     313            // ceil(80000/256)

__device__ __forceinline__ float lrelu(float v) { return v >= 0.f ? v : NEGS * v; }

// ---------- CSR build (dst and src), once per call ----------
__global__ void k_count2(const int* __restrict__ ei, int* __restrict__ cntD,
                         int* __restrict__ cntS) {
  int e = blockIdx.x * blockDim.x + threadIdx.x;
  if (e >= NEDGE) return;
  atomicAdd(&cntD[ei[NEDGE + e]], 1);
  atomicAdd(&cntS[ei[e]], 1);
}

// in-place exclusive scan, stage 1: per-block scan + block sums
__global__ void k_scan1(int* __restrict__ data, int* __restrict__ bsum) {
  __shared__ int tmp[256];
  int i = blockIdx.x * 256 + threadIdx.x;
  int v = (i < NNODES) ? data[i] : 0;
  tmp[threadIdx.x] = v;
  __syncthreads();
  for (int off = 1; off < 256; off <<= 1) {
    int t = (threadIdx.x >= off) ? tmp[threadIdx.x - off] : 0;
    __syncthreads();
    tmp[threadIdx.x] += t;
    __syncthreads();
  }
  if (i < NNODES) data[i] = tmp[threadIdx.x] - v;   // exclusive
  if (threadIdx.x == 255) bsum[blockIdx.x] = tmp[255];
}

__global__ void k_scan2(int* __restrict__ bsum, int* __restrict__ bex) {
  __shared__ int tmp[512];
  int v = (threadIdx.x < NBLK) ? bsum[threadIdx.x] : 0;
  tmp[threadIdx.x] = v;
  __syncthreads();
  for (int off = 1; off < 512; off <<= 1) {
    int t = (threadIdx.x >= off) ? tmp[threadIdx.x - off] : 0;
    __syncthreads();
    tmp[threadIdx.x] += t;
    __syncthreads();
  }
  if (threadIdx.x < NBLK) bex[threadIdx.x] = tmp[threadIdx.x] - v;
}

__global__ void k_scan3(int* __restrict__ data, const int* __restrict__ bex) {
  int i = blockIdx.x * 256 + threadIdx.x;
  if (i < NNODES) data[i] += bex[blockIdx.x];
  if (i == 0) data[NNODES] = NEDGE;
}

// fill both CSRs:
//   src list stores the edge's DST node; dst list stores (src, posS)
__global__ void k_fill2(const int* __restrict__ ei, const int* __restrict__ rowptrD,
                        const int* __restrict__ rowptrS, int* __restrict__ fcD,
                        int* __restrict__ fcS, int2* __restrict__ eD,
                        int* __restrict__ eSd) {
  int e = blockIdx.x * blockDim.x + threadIdx.x;
  if (e >= NEDGE) return;
  int s = ei[e];
  int d = ei[NEDGE + e];
  int posS = rowptrS[s] + atomicAdd(&fcS[s], 1);
  eSd[posS] = d;
  int posD = rowptrD[d] + atomicAdd(&fcD[d], 1);
  eD[posD] = make_int2(s, posS);
}

// ---------- layer-1 GEMM (K=8): W1 in registers ----------
__global__ void k_gemm_in(const float* __restrict__ x, const float* __restrict__ W,
                          float* __restrict__ h) {
  int tid = blockIdx.x * blockDim.x + threadIdx.x;
  int tx = tid & 15;
  int c0 = tx * 8;
  float4 wv[16];
#pragma unroll
  for (int j = 0; j < 8; j++) {
    wv[j * 2 + 0] = *(const float4*)(W + (size_t)(c0 + j) * IN_DIM);
    wv[j * 2 + 1] = *(const float4*)(W + (size_t)(c0 + j) * IN_DIM + 4);
  }
  int stride = (gridDim.x * blockDim.x) >> 4;
  for (int n = tid >> 4; n < NNODES; n += stride) {
    float4 x0 = *(const float4*)(x + (size_t)n * IN_DIM);
    float4 x1 = *(const float4*)(x + (size_t)n * IN_DIM + 4);
    float o[8];
#pragma unroll
    for (int j = 0; j < 8; j++) {
      float4 a = wv[j * 2], b = wv[j * 2 + 1];
      o[j] = x0.x*a.x + x0.y*a.y + x0.z*a.z + x0.w*a.w
           + x1.x*b.x + x1.y*b.y + x1.z*b.z + x1.w*b.w;
    }
    float4* hp = (float4*)(h + (size_t)n * HID + c0);
    hp[0] = make_float4(o[0], o[1], o[2], o[3]);
    hp[1] = make_float4(o[4], o[5], o[6], o[7]);
  }
}

// ---------- 128x128 GEMM with fused input BN+lrelu: 8x8 per thread, W^T in LDS ----------
// h = lrelu(y*scale+shift) @ W.T   (BN applied on the fly to each loaded x element)
#define GB_NODES 128
__global__ __launch_bounds__(256, 2)
void k_gemm128_bn(const float* __restrict__ y, const float* __restrict__ scale,
                  const float* __restrict__ shift, const float* __restrict__ W,
                  float* __restrict__ h) {
  __shared__ float sw[HID][HID + 4];
  __shared__ float sscale[HID], sshift[HID];
  int tid = threadIdx.x;
  if (tid < HID) { sscale[tid] = scale[tid]; sshift[tid] = shift[tid]; }
  for (int idx = tid * 4; idx < HID * HID; idx += 256 * 4) {
    int c = idx >> 7, k = idx & 127;
    float4 w = *(const float4*)(W + (size_t)c * HID + k);
    sw[k + 0][c] = w.x; sw[k + 1][c] = w.y; sw[k + 2][c] = w.z; sw[k + 3][c] = w.w;
  }
  __syncthreads();
  int tx = tid & 15, ty = tid >> 4;
  int n0 = blockIdx.x * GB_NODES + ty * 8;
  int c0 = tx * 8;
  float acc[8][8];
#pragma unroll
  for (int i = 0; i < 8; i++)
#pragma unroll
    for (int j = 0; j < 8; j++) acc[i][j] = 0.f;

  const float* xp = y + (size_t)n0 * HID;
  for (int kk = 0; kk < HID; kk += 4) {
    float4 sc = *(const float4*)&sscale[kk];
    float4 sh = *(const float4*)&sshift[kk];
    float4 xv[8];
#pragma unroll
    for (int i = 0; i < 8; i++) {
      float4 v = *(const float4*)(xp + (size_t)i * HID + kk);
      v.x = lrelu(v.x * sc.x + sh.x);
      v.y = lrelu(v.y * sc.y + sh.y);
      v.z = lrelu(v.z * sc.z + sh.z);
      v.w = lrelu(v.w * sc.w + sh.w);
      xv[i] = v;
    }
#pragma unroll
    for (int k4 = 0; k4 < 4; k4++) {
      float4 w0 = *(const float4*)&sw[kk + k4][c0];
      float4 w1 = *(const float4*)&sw[kk + k4][c0 + 4];
      float wj[8] = { w0.x, w0.y, w0.z, w0.w, w1.x, w1.y, w1.z, w1.w };
#pragma unroll
      for (int i = 0; i < 8; i++) {
        const float* xe = (const float*)&xv[i];
        float xs = xe[k4];
#pragma unroll
        for (int j = 0; j < 8; j++) acc[i][j] += xs * wj[j];
      }
    }
  }
#pragma unroll
  for (int i = 0; i < 8; i++) {
    float4* hp = (float4*)(h + (size_t)(n0 + i) * HID + c0);
    hp[0] = make_float4(acc[i][0], acc[i][1], acc[i][2], acc[i][3]);
    hp[1] = make_float4(acc[i][4], acc[i][5], acc[i][6], acc[i][7]);
  }
}

__global__ void k_att_node(const float* __restrict__ h, const float* __restrict__ att,
                           float* __restrict__ aL, float* __restrict__ aR) {
  __shared__ float satt[HEADS * 2 * KH];
  for (int i = threadIdx.x; i < HEADS * 2 * KH; i += blockDim.x) satt[i] = att[i];
  __syncthreads();
  int total = NNODES * HEADS;
  for (int idx = blockIdx.x * blockDim.x + threadIdx.x; idx < total;
       idx += gridDim.x * blockDim.x) {
    int n = idx >> 3, hd = idx & 7;
    const float* hp  = h + (size_t)n * HID + hd * KH;
    const float* aLw = satt + hd * 2 * KH;
    const float* aRw = aLw + KH;
    float sl = 0.f, sr = 0.f;
#pragma unroll
    for (int c = 0; c < KH; c++) { float v = hp[c]; sl += v * aLw[c]; sr += v * aRw[c]; }
    aL[idx] = sl; aR[idx] = sr;
  }
}

// per (node, head): online softmax over out-edges, a computed on the fly
__global__ void k_src_softmax(const int* __restrict__ rowptrS, const int* __restrict__ eSd,
                              const float* __restrict__ aL, const float* __restrict__ aR,
                              float* __restrict__ alphaS, float* __restrict__ aself) {
  int t = blockIdx.x * blockDim.x + threadIdx.x;
  int n = t >> 3;
  if (n >= NNODES) return;
  int hd = t & 7;
  int sh = n * 8 + hd;
  float aRn = aR[sh];
  float aself_a = lrelu(aL[sh] + aRn);
  float m = aself_a, l = 1.f;
  int j0 = rowptrS[n], j1 = rowptrS[n + 1];
  for (int j = j0; j < j1; j++) {
    int d = eSd[j];
    float a = lrelu(aL[d * 8 + hd] + aRn);
    alphaS[(size_t)j * 8 + hd] = a;
    if (a > m) { l = l * __expf(m - a) + 1.f; m = a; }
    else       { l += __expf(a - m); }
  }
  float rinv = 1.f / (l + 1e-16f);
  aself[sh] = __expf(aself_a - m) * rinv;
  for (int j = j0; j < j1; j++) {
    size_t idx = (size_t)j * 8 + hd;
    alphaS[idx] = __expf(alphaS[idx] - m) * rinv;
  }
}

// gather aggregation via dst-CSR; fuse bias+relu
__global__ __launch_bounds__(256)
void k_agg_gather(const int* __restrict__ rowptrD, const int2* __restrict__ eD,
                  const float* __restrict__ alphaS, const float* __restrict__ aself,
                  const float* __restrict__ h, const float* __restrict__ bias,
                  float* __restrict__ yout) {
  int node = blockIdx.x * 2 + (threadIdx.x >> 7);
  if (node >= NNODES) return;
  int c = threadIdx.x & 127;
  int hd = c >> 4;
  float acc = aself[node * 8 + hd] * h[(size_t)node * HID + c];
  int j = rowptrD[node], j1 = rowptrD[node + 1];
  for (; j + 1 < j1; j += 2) {
    int2 p0 = eD[j], p1 = eD[j + 1];
    float al0 = alphaS[(size_t)p0.y * 8 + hd];
    float al1 = alphaS[(size_t)p1.y * 8 + hd];
    float h0 = h[(size_t)p0.x * HID + c];
    float h1 = h[(size_t)p1.x * HID + c];
    acc += al0 * h0 + al1 * h1;
  }
  if (j < j1) {
    int2 p0 = eD[j];
    acc += alphaS[(size_t)p0.y * 8 + hd] * h[(size_t)p0.x * HID + c];
  }
  float v = acc + bias[c];
  yout[(size_t)node * HID + c] = v > 0.f ? v : 0.f;
}

// BN statistics (read-only over y)
__global__ void k_bnstats(const float* __restrict__ y, double* __restrict__ bnsum,
                          double* __restrict__ bnsq) {
  int c = threadIdx.x;
  float s = 0.f, sq = 0.f;
  for (int n = blockIdx.x; n < NNODES; n += gridDim.x) {
    float v = y[(size_t)n * HID + c];
    s += v; sq += v * v;
  }
  atomicAdd(&bnsum[c], (double)s);
  atomicAdd(&bnsq[c], (double)sq);
}

__global__ void k_bnfinal(const double* __restrict__ bnsum, const double* __restrict__ bnsq,
                          const float* __restrict__ g, const float* __restrict__ be,
                          float* __restrict__ scale, float* __restrict__ shift) {
  int c = threadIdx.x;
  double mean = bnsum[c] / (double)NNODES;
  double var  = bnsq[c] / (double)NNODES - mean * mean;
  float rs = (float)(1.0 / sqrt(var + (double)EPSBN));
  float sc = g[c] * rs;
  scale[c] = sc;
  shift[c] = be[c] - (float)mean * sc;
}

// power-mean partial sums with fused BN+lrelu (layer-3 BN applied here)
__global__ void k_pmean_bn(const float* __restrict__ y, const float* __restrict__ scale,
                           const float* __restrict__ shift, const float* __restrict__ p_,
                           float* __restrict__ xgsum) {
  int b = blockIdx.y, c = threadIdx.x;
  float p = p_[0];
  float sc = scale[c], sh = shift[c];
  int rows_per = (PERB + gridDim.x - 1) / gridDim.x;
  int r0 = blockIdx.x * rows_per;
  int r1 = r0 + rows_per; if (r1 > PERB) r1 = PERB;
  float acc = 0.f;
  for (int i = r0; i < r1; i++) {
    float v = y[((size_t)b * PERB + i) * HID + c];
    v = lrelu(v * sc + sh);
    v = fminf(fmaxf(v, 0.f), 100.f);
    acc += powf(v, p);
  }
  atomicAdd(&xgsum[b * HID + c], acc);
}

__global__ void k_head(const float* __restrict__ xgsum, const float* __restrict__ p_,
                       const float* __restrict__ Wg, const float* __restrict__ bg,
                       float* __restrict__ out) {
  __shared__ float sxg[HID];
  __shared__ float red[HID];
  int b = blockIdx.x, c = threadIdx.x;
  float p = p_[0];
  float m = xgsum[b * HID + c] / (float)PERB;
  m = fminf(fmaxf(m, 0.f), 100.f);
  sxg[c] = powf(m, 1.0f / p);
  __syncthreads();
  float l0 = 0.f, l1 = 0.f;
  for (int j = 0; j < 2; j++) {
    red[c] = sxg[c] * Wg[j * HID + c];
    __syncthreads();
    for (int off = 64; off > 0; off >>= 1) {
      if (c < off) red[c] += red[c + off];
      __syncthreads();
    }
    if (c == 0) { if (j == 0) l0 = red[0] + bg[0]; else l1 = red[0] + bg[1]; }
    __syncthreads();
  }
  if (c == 0) {
    out[b * 2 + 0] = l0;
    out[b * 2 + 1] = l1;
    out[2 * BATCH + b] = (l1 > l0) ? 1.0f : 0.0f;
  }
}

extern "C" void kernel_launch(void* const* d_in, const int* in_sizes, int n_in,
                              void* d_out, int out_size, void* d_ws, size_t ws_size,
                              hipStream_t stream) {
  (void)in_sizes; (void)n_in; (void)out_size; (void)ws_size;
  const float* x    = (const float*)d_in[0];
  const int*   ei   = (const int*)d_in[1];
  const float* Wl[3]   = { (const float*)d_in[2],  (const float*)d_in[7],  (const float*)d_in[12] };
  const float* attl[3] = { (const float*)d_in[3],  (const float*)d_in[8],  (const float*)d_in[13] };
  const float* bl[3]   = { (const float*)d_in[4],  (const float*)d_in[9],  (const float*)d_in[14] };
  const float* gl[3]   = { (const float*)d_in[5],  (const float*)d_in[10], (const float*)d_in[15] };
  const float* bel[3]  = { (const float*)d_in[6],  (const float*)d_in[11], (const float*)d_in[16] };
  const float* p    = (const float*)d_in[17];
  const float* Wg   = (const float*)d_in[18];
  const float* bg   = (const float*)d_in[19];
  float* out = (float*)d_out;

  float* ws   = (float*)d_ws;
  float* h    = ws;                                  // N*128
  float* agg  = h    + (size_t)NNODES * HID;         // N*128 (= y, pre-BN)
  float* xbuf = agg  + (size_t)NNODES * HID;         // N*128 (only used as alphaS now)
  float* aL   = xbuf + (size_t)NNODES * HID;         // N*8
  float* aR   = aL   + (size_t)NNODES * HEADS;
  float* aself= aR   + (size_t)NNODES * HEADS;       // N*8
  double* bnsum = (double*)(aself + (size_t)NNODES * HEADS);
  double* bnsq  = bnsum + HID;
  float* scale  = (float*)(bnsq + HID);
  float* shift  = scale + HID;
  float* xgsum  = shift + HID;                       // 8*128
  // CSR scratch (after xgsum; float offset is even -> 8B aligned for int2)
  int2* eD      = (int2*)(xgsum + BATCH * HID);      // NEDGE pairs (src, posS)
  int*  eSd     = (int*)(eD + NEDGE);                // NEDGE (dst per src-ordered edge)
  int* rowptrD  = eSd + NEDGE;                       // N+1
  int* rowptrS  = rowptrD + (NNODES + 1);            // N+1
  int* fcD      = rowptrS + (NNODES + 1);            // N
  int* fcS      = fcD + NNODES;                      // N
  int* bsum     = fcS + NNODES;                      // NBLK
  int* bex      = bsum + NBLK;                       // NBLK
  float* alphaS = xbuf;                              // NEDGE*8 == N*128 exactly

  // ---- build dst-CSR and src-CSR ----
  hipMemsetAsync(rowptrD, 0, sizeof(int) * (4 * NNODES + 2), stream);
  k_count2<<<(NEDGE + 255) / 256, 256, 0, stream>>>(ei, rowptrD, rowptrS);
  k_scan1<<<NBLK, 256, 0, stream>>>(rowptrD, bsum);
  k_scan2<<<1, 512, 0, stream>>>(bsum, bex);
  k_scan3<<<NBLK, 256, 0, stream>>>(rowptrD, bex);
  k_scan1<<<NBLK, 256, 0, stream>>>(rowptrS, bsum);
  k_scan2<<<1, 512, 0, stream>>>(bsum, bex);
  k_scan3<<<NBLK, 256, 0, stream>>>(rowptrS, bex);
  k_fill2<<<(NEDGE + 255) / 256, 256, 0, stream>>>(ei, rowptrD, rowptrS, fcD, fcS, eD, eSd);

  for (int layer = 0; layer < 3; layer++) {
    if (layer == 0) k_gemm_in<<<2048, 256, 0, stream>>>(x, Wl[0], h);
    else            k_gemm128_bn<<<NNODES / GB_NODES, 256, 0, stream>>>(agg, scale, shift,
                                                                        Wl[layer], h);

    k_att_node<<<2500, 256, 0, stream>>>(h, attl[layer], aL, aR);

    k_src_softmax<<<(NNODES * 8 + 255) / 256, 256, 0, stream>>>(rowptrS, eSd, aL, aR, alphaS, aself);
    k_agg_gather<<<NNODES / 2, 256, 0, stream>>>(rowptrD, eD, alphaS, aself, h, bl[layer], agg);

    hipMemsetAsync(bnsum, 0, sizeof(double) * HID * 2, stream);
    k_bnstats<<<1024, 128, 0, stream>>>(agg, bnsum, bnsq);
    k_bnfinal<<<1, 128, 0, stream>>>(bnsum, bnsq, gl[layer], bel[layer], scale, shift);
  }

  hipMemsetAsync(xgsum, 0, sizeof(float) * BATCH * HID, stream);
  k_pmean_bn<<<dim3(256, BATCH), 128, 0, stream>>>(agg, scale, shift, p, xgsum);
  k_head<<<BATCH, 128, 0, stream>>>(xgsum, p, Wg, bg, out);
}

// Round 10
// 1310.054 us; speedup vs baseline: 3.6173x; 1.0879x over previous
//
#include <hip/hip_runtime.h>
#include <hip/hip_fp16.h>
#include <math.h>

#define NNODES   80000
#define IN_DIM   8
#define HID      128
#define HEADS    8
#define KH       16
#define NEDGE    1280000
#define NETOT    (NEDGE + NNODES)
#define NEGS     0.2f
#define EPSBN    1e-5f
#define BATCH    8
#define PERB     10000
#define NBLK     313            // ceil(80000/256)

__device__ __forceinline__ float lrelu(float v) { return v >= 0.f ? v : NEGS * v; }

// ---------- CSR build (dst and src), once per call ----------
__global__ void k_count2(const int* __restrict__ ei, int* __restrict__ cntD,
                         int* __restrict__ cntS) {
  int e = blockIdx.x * blockDim.x + threadIdx.x;
  if (e >= NEDGE) return;
  atomicAdd(&cntD[ei[NEDGE + e]], 1);
  atomicAdd(&cntS[ei[e]], 1);
}

__global__ void k_scan1(int* __restrict__ data, int* __restrict__ bsum) {
  __shared__ int tmp[256];
  int i = blockIdx.x * 256 + threadIdx.x;
  int v = (i < NNODES) ? data[i] : 0;
  tmp[threadIdx.x] = v;
  __syncthreads();
  for (int off = 1; off < 256; off <<= 1) {
    int t = (threadIdx.x >= off) ? tmp[threadIdx.x - off] : 0;
    __syncthreads();
    tmp[threadIdx.x] += t;
    __syncthreads();
  }
  if (i < NNODES) data[i] = tmp[threadIdx.x] - v;   // exclusive
  if (threadIdx.x == 255) bsum[blockIdx.x] = tmp[255];
}

__global__ void k_scan2(int* __restrict__ bsum, int* __restrict__ bex) {
  __shared__ int tmp[512];
  int v = (threadIdx.x < NBLK) ? bsum[threadIdx.x] : 0;
  tmp[threadIdx.x] = v;
  __syncthreads();
  for (int off = 1; off < 512; off <<= 1) {
    int t = (threadIdx.x >= off) ? tmp[threadIdx.x - off] : 0;
    __syncthreads();
    tmp[threadIdx.x] += t;
    __syncthreads();
  }
  if (threadIdx.x < NBLK) bex[threadIdx.x] = tmp[threadIdx.x] - v;
}

__global__ void k_scan3(int* __restrict__ data, const int* __restrict__ bex) {
  int i = blockIdx.x * 256 + threadIdx.x;
  if (i < NNODES) data[i] += bex[blockIdx.x];
  if (i == 0) data[NNODES] = NEDGE;
}

// fill both CSRs: src list stores the edge's DST node; dst list stores src only
__global__ void k_fill2(const int* __restrict__ ei, const int* __restrict__ rowptrD,
                        const int* __restrict__ rowptrS, int* __restrict__ fcD,
                        int* __restrict__ fcS, int* __restrict__ eD,
                        int* __restrict__ eSd) {
  int e = blockIdx.x * blockDim.x + threadIdx.x;
  if (e >= NEDGE) return;
  int s = ei[e];
  int d = ei[NEDGE + e];
  int posS = rowptrS[s] + atomicAdd(&fcS[s], 1);
  eSd[posS] = d;
  int posD = rowptrD[d] + atomicAdd(&fcD[d], 1);
  eD[posD] = s;
}

// ---------- layer-1 GEMM (K=8): W1 in registers; h stored fp16 ----------
__global__ void k_gemm_in(const float* __restrict__ x, const float* __restrict__ W,
                          __half* __restrict__ hh) {
  int tid = blockIdx.x * blockDim.x + threadIdx.x;
  int tx = tid & 15;
  int c0 = tx * 8;
  float4 wv[16];
#pragma unroll
  for (int j = 0; j < 8; j++) {
    wv[j * 2 + 0] = *(const float4*)(W + (size_t)(c0 + j) * IN_DIM);
    wv[j * 2 + 1] = *(const float4*)(W + (size_t)(c0 + j) * IN_DIM + 4);
  }
  int stride = (gridDim.x * blockDim.x) >> 4;
  for (int n = tid >> 4; n < NNODES; n += stride) {
    float4 x0 = *(const float4*)(x + (size_t)n * IN_DIM);
    float4 x1 = *(const float4*)(x + (size_t)n * IN_DIM + 4);
    float o[8];
#pragma unroll
    for (int j = 0; j < 8; j++) {
      float4 a = wv[j * 2], b = wv[j * 2 + 1];
      o[j] = x0.x*a.x + x0.y*a.y + x0.z*a.z + x0.w*a.w
           + x1.x*b.x + x1.y*b.y + x1.z*b.z + x1.w*b.w;
    }
    __half2* hp = (__half2*)(hh + (size_t)n * HID + c0);
    hp[0] = __floats2half2_rn(o[0], o[1]);
    hp[1] = __floats2half2_rn(o[2], o[3]);
    hp[2] = __floats2half2_rn(o[4], o[5]);
    hp[3] = __floats2half2_rn(o[6], o[7]);
  }
}

// ---------- 128x128 GEMM with fused input BN+lrelu; h stored fp16 ----------
#define GB_NODES 128
__global__ __launch_bounds__(256, 2)
void k_gemm128_bn(const float* __restrict__ y, const float* __restrict__ scale,
                  const float* __restrict__ shift, const float* __restrict__ W,
                  __half* __restrict__ hh) {
  __shared__ float sw[HID][HID + 4];
  __shared__ float sscale[HID], sshift[HID];
  int tid = threadIdx.x;
  if (tid < HID) { sscale[tid] = scale[tid]; sshift[tid] = shift[tid]; }
  for (int idx = tid * 4; idx < HID * HID; idx += 256 * 4) {
    int c = idx >> 7, k = idx & 127;
    float4 w = *(const float4*)(W + (size_t)c * HID + k);
    sw[k + 0][c] = w.x; sw[k + 1][c] = w.y; sw[k + 2][c] = w.z; sw[k + 3][c] = w.w;
  }
  __syncthreads();
  int tx = tid & 15, ty = tid >> 4;
  int n0 = blockIdx.x * GB_NODES + ty * 8;
  int c0 = tx * 8;
  float acc[8][8];
#pragma unroll
  for (int i = 0; i < 8; i++)
#pragma unroll
    for (int j = 0; j < 8; j++) acc[i][j] = 0.f;

  const float* xp = y + (size_t)n0 * HID;
  for (int kk = 0; kk < HID; kk += 4) {
    float4 sc = *(const float4*)&sscale[kk];
    float4 sh = *(const float4*)&sshift[kk];
    float4 xv[8];
#pragma unroll
    for (int i = 0; i < 8; i++) {
      float4 v = *(const float4*)(xp + (size_t)i * HID + kk);
      v.x = lrelu(v.x * sc.x + sh.x);
      v.y = lrelu(v.y * sc.y + sh.y);
      v.z = lrelu(v.z * sc.z + sh.z);
      v.w = lrelu(v.w * sc.w + sh.w);
      xv[i] = v;
    }
#pragma unroll
    for (int k4 = 0; k4 < 4; k4++) {
      float4 w0 = *(const float4*)&sw[kk + k4][c0];
      float4 w1 = *(const float4*)&sw[kk + k4][c0 + 4];
      float wj[8] = { w0.x, w0.y, w0.z, w0.w, w1.x, w1.y, w1.z, w1.w };
#pragma unroll
      for (int i = 0; i < 8; i++) {
        const float* xe = (const float*)&xv[i];
        float xs = xe[k4];
#pragma unroll
        for (int j = 0; j < 8; j++) acc[i][j] += xs * wj[j];
      }
    }
  }
#pragma unroll
  for (int i = 0; i < 8; i++) {
    __half2* hp = (__half2*)(hh + (size_t)(n0 + i) * HID + c0);
    hp[0] = __floats2half2_rn(acc[i][0], acc[i][1]);
    hp[1] = __floats2half2_rn(acc[i][2], acc[i][3]);
    hp[2] = __floats2half2_rn(acc[i][4], acc[i][5]);
    hp[3] = __floats2half2_rn(acc[i][6], acc[i][7]);
  }
}

__global__ void k_att_node(const __half* __restrict__ hh, const float* __restrict__ att,
                           float* __restrict__ aL, float* __restrict__ aR) {
  __shared__ float satt[HEADS * 2 * KH];
  for (int i = threadIdx.x; i < HEADS * 2 * KH; i += blockDim.x) satt[i] = att[i];
  __syncthreads();
  int total = NNODES * HEADS;
  for (int idx = blockIdx.x * blockDim.x + threadIdx.x; idx < total;
       idx += gridDim.x * blockDim.x) {
    int n = idx >> 3, hd = idx & 7;
    const __half* hp = hh + (size_t)n * HID + hd * KH;
    const float* aLw = satt + hd * 2 * KH;
    const float* aRw = aLw + KH;
    float sl = 0.f, sr = 0.f;
#pragma unroll
    for (int c = 0; c < KH; c++) {
      float v = __half2float(hp[c]);
      sl += v * aLw[c]; sr += v * aRw[c];
    }
    aL[idx] = sl; aR[idx] = sr;
  }
}

// per (node, head): online softmax stats over out-edges; packs
// (aR, m, rinv, alpha_self) into float4 pk. No alpha array, single pass.
__global__ void k_src_softmax(const int* __restrict__ rowptrS, const int* __restrict__ eSd,
                              const float* __restrict__ aL, const float* __restrict__ aR,
                              float4* __restrict__ pk) {
  int t = blockIdx.x * blockDim.x + threadIdx.x;
  int n = t >> 3;
  if (n >= NNODES) return;
  int hd = t & 7;
  int sh = n * 8 + hd;
  float aRn = aR[sh];
  float aself_a = lrelu(aL[sh] + aRn);
  float m = aself_a, l = 1.f;
  int j0 = rowptrS[n], j1 = rowptrS[n + 1];
  for (int j = j0; j < j1; j++) {
    int d = eSd[j];
    float a = lrelu(aL[d * 8 + hd] + aRn);
    if (a > m) { l = l * __expf(m - a) + 1.f; m = a; }
    else       { l += __expf(a - m); }
  }
  float rinv = 1.f / (l + 1e-16f);
  pk[sh] = make_float4(aRn, m, rinv, __expf(aself_a - m) * rinv);
}

// gather aggregation via dst-CSR; alpha computed on the fly; fuse bias+relu
__global__ __launch_bounds__(256)
void k_agg_gather(const int* __restrict__ rowptrD, const int* __restrict__ eD,
                  const float4* __restrict__ pk, const float* __restrict__ aL,
                  const __half* __restrict__ hh, const float* __restrict__ bias,
                  float* __restrict__ yout) {
  int node = blockIdx.x * 2 + (threadIdx.x >> 7);
  if (node >= NNODES) return;
  int c = threadIdx.x & 127;
  int hd = c >> 4;
  float aln = aL[node * 8 + hd];
  float4 pkn = pk[node * 8 + hd];
  float acc = pkn.w * __half2float(hh[(size_t)node * HID + c]);
  int j = rowptrD[node], j1 = rowptrD[node + 1];
  for (; j + 1 < j1; j += 2) {
    int s0 = eD[j], s1 = eD[j + 1];
    float4 q0 = pk[s0 * 8 + hd];
    float4 q1 = pk[s1 * 8 + hd];
    float h0 = __half2float(hh[(size_t)s0 * HID + c]);
    float h1 = __half2float(hh[(size_t)s1 * HID + c]);
    float al0 = __expf(lrelu(aln + q0.x) - q0.y) * q0.z;
    float al1 = __expf(lrelu(aln + q1.x) - q1.y) * q1.z;
    acc += al0 * h0 + al1 * h1;
  }
  if (j < j1) {
    int s0 = eD[j];
    float4 q0 = pk[s0 * 8 + hd];
    acc += __expf(lrelu(aln + q0.x) - q0.y) * q0.z * __half2float(hh[(size_t)s0 * HID + c]);
  }
  float v = acc + bias[c];
  yout[(size_t)node * HID + c] = v > 0.f ? v : 0.f;
}

// BN statistics (read-only over y)
__global__ void k_bnstats(const float* __restrict__ y, double* __restrict__ bnsum,
                          double* __restrict__ bnsq) {
  int c = threadIdx.x;
  float s = 0.f, sq = 0.f;
  for (int n = blockIdx.x; n < NNODES; n += gridDim.x) {
    float v = y[(size_t)n * HID + c];
    s += v; sq += v * v;
  }
  atomicAdd(&bnsum[c], (double)s);
  atomicAdd(&bnsq[c], (double)sq);
}

__global__ void k_bnfinal(const double* __restrict__ bnsum, const double* __restrict__ bnsq,
                          const float* __restrict__ g, const float* __restrict__ be,
                          float* __restrict__ scale, float* __restrict__ shift) {
  int c = threadIdx.x;
  double mean = bnsum[c] / (double)NNODES;
  double var  = bnsq[c] / (double)NNODES - mean * mean;
  float rs = (float)(1.0 / sqrt(var + (double)EPSBN));
  float sc = g[c] * rs;
  scale[c] = sc;
  shift[c] = be[c] - (float)mean * sc;
}

// power-mean partial sums with fused BN+lrelu (layer-3 BN applied here)
__global__ void k_pmean_bn(const float* __restrict__ y, const float* __restrict__ scale,
                           const float* __restrict__ shift, const float* __restrict__ p_,
                           float* __restrict__ xgsum) {
  int b = blockIdx.y, c = threadIdx.x;
  float p = p_[0];
  float sc = scale[c], sh = shift[c];
  int rows_per = (PERB + gridDim.x - 1) / gridDim.x;
  int r0 = blockIdx.x * rows_per;
  int r1 = r0 + rows_per; if (r1 > PERB) r1 = PERB;
  float acc = 0.f;
  for (int i = r0; i < r1; i++) {
    float v = y[((size_t)b * PERB + i) * HID + c];
    v = lrelu(v * sc + sh);
    v = fminf(fmaxf(v, 0.f), 100.f);
    acc += powf(v, p);
  }
  atomicAdd(&xgsum[b * HID + c], acc);
}

__global__ void k_head(const float* __restrict__ xgsum, const float* __restrict__ p_,
                       const float* __restrict__ Wg, const float* __restrict__ bg,
                       float* __restrict__ out) {
  __shared__ float sxg[HID];
  __shared__ float red[HID];
  int b = blockIdx.x, c = threadIdx.x;
  float p = p_[0];
  float m = xgsum[b * HID + c] / (float)PERB;
  m = fminf(fmaxf(m, 0.f), 100.f);
  sxg[c] = powf(m, 1.0f / p);
  __syncthreads();
  float l0 = 0.f, l1 = 0.f;
  for (int j = 0; j < 2; j++) {
    red[c] = sxg[c] * Wg[j * HID + c];
    __syncthreads();
    for (int off = 64; off > 0; off >>= 1) {
      if (c < off) red[c] += red[c + off];
      __syncthreads();
    }
    if (c == 0) { if (j == 0) l0 = red[0] + bg[0]; else l1 = red[0] + bg[1]; }
    __syncthreads();
  }
  if (c == 0) {
    out[b * 2 + 0] = l0;
    out[b * 2 + 1] = l1;
    out[2 * BATCH + b] = (l1 > l0) ? 1.0f : 0.0f;
  }
}

extern "C" void kernel_launch(void* const* d_in, const int* in_sizes, int n_in,
                              void* d_out, int out_size, void* d_ws, size_t ws_size,
                              hipStream_t stream) {
  (void)in_sizes; (void)n_in; (void)out_size; (void)ws_size;
  const float* x    = (const float*)d_in[0];
  const int*   ei   = (const int*)d_in[1];
  const float* Wl[3]   = { (const float*)d_in[2],  (const float*)d_in[7],  (const float*)d_in[12] };
  const float* attl[3] = { (const float*)d_in[3],  (const float*)d_in[8],  (const float*)d_in[13] };
  const float* bl[3]   = { (const float*)d_in[4],  (const float*)d_in[9],  (const float*)d_in[14] };
  const float* gl[3]   = { (const float*)d_in[5],  (const float*)d_in[10], (const float*)d_in[15] };
  const float* bel[3]  = { (const float*)d_in[6],  (const float*)d_in[11], (const float*)d_in[16] };
  const float* p    = (const float*)d_in[17];
  const float* Wg   = (const float*)d_in[18];
  const float* bg   = (const float*)d_in[19];
  float* out = (float*)d_out;

  float* ws   = (float*)d_ws;
  __half* hh  = (__half*)ws;                         // N*128 halfs = N*64 floats
  float* agg  = ws + (size_t)NNODES * (HID / 2);     // N*128 floats (= y, pre-BN)
  float* aL   = agg + (size_t)NNODES * HID;          // N*8
  float* aR   = aL  + (size_t)NNODES * HEADS;        // N*8
  float4* pk  = (float4*)(aR + (size_t)NNODES * HEADS);  // N*8 float4 (16B-aligned offset)
  double* bnsum = (double*)(pk + (size_t)NNODES * HEADS);
  double* bnsq  = bnsum + HID;
  float* scale  = (float*)(bnsq + HID);
  float* shift  = scale + HID;
  float* xgsum  = shift + HID;                       // 8*128
  int* eD       = (int*)(xgsum + BATCH * HID);       // NEDGE (src per dst-ordered edge)
  int* eSd      = eD + NEDGE;                        // NEDGE (dst per src-ordered edge)
  int* rowptrD  = eSd + NEDGE;                       // N+1
  int* rowptrS  = rowptrD + (NNODES + 1);            // N+1
  int* fcD      = rowptrS + (NNODES + 1);            // N
  int* fcS      = fcD + NNODES;                      // N
  int* bsum     = fcS + NNODES;                      // NBLK
  int* bex      = bsum + NBLK;                       // NBLK

  // ---- build dst-CSR and src-CSR ----
  hipMemsetAsync(rowptrD, 0, sizeof(int) * (4 * NNODES + 2), stream);
  k_count2<<<(NEDGE + 255) / 256, 256, 0, stream>>>(ei, rowptrD, rowptrS);
  k_scan1<<<NBLK, 256, 0, stream>>>(rowptrD, bsum);
  k_scan2<<<1, 512, 0, stream>>>(bsum, bex);
  k_scan3<<<NBLK, 256, 0, stream>>>(rowptrD, bex);
  k_scan1<<<NBLK, 256, 0, stream>>>(rowptrS, bsum);
  k_scan2<<<1, 512, 0, stream>>>(bsum, bex);
  k_scan3<<<NBLK, 256, 0, stream>>>(rowptrS, bex);
  k_fill2<<<(NEDGE + 255) / 256, 256, 0, stream>>>(ei, rowptrD, rowptrS, fcD, fcS, eD, eSd);

  for (int layer = 0; layer < 3; layer++) {
    if (layer == 0) k_gemm_in<<<2048, 256, 0, stream>>>(x, Wl[0], hh);
    else            k_gemm128_bn<<<NNODES / GB_NODES, 256, 0, stream>>>(agg, scale, shift,
                                                                        Wl[layer], hh);

    k_att_node<<<2500, 256, 0, stream>>>(hh, attl[layer], aL, aR);

    k_src_softmax<<<(NNODES * 8 + 255) / 256, 256, 0, stream>>>(rowptrS, eSd, aL, aR, pk);
    k_agg_gather<<<NNODES / 2, 256, 0, stream>>>(rowptrD, eD, pk, aL, hh, bl[layer], agg);

    hipMemsetAsync(bnsum, 0, sizeof(double) * HID * 2, stream);
    k_bnstats<<<1024, 128, 0, stream>>>(agg, bnsum, bnsq);
    k_bnfinal<<<1, 128, 0, stream>>>(bnsum, bnsq, gl[layer], bel[layer], scale, shift);
  }

  hipMemsetAsync(xgsum, 0, sizeof(float) * BATCH * HID, stream);
  k_pmean_bn<<<dim3(256, BATCH), 128, 0, stream>>>(agg, scale, shift, p, xgsum);
  k_head<<<BATCH, 128, 0, stream>>>(xgsum, p, Wg, bg, out);
}

// Round 12
// 1098.913 us; speedup vs baseline: 4.3123x; 1.1921x over previous
//
#include <hip/hip_runtime.h>
#include <hip/hip_fp16.h>
#include <math.h>

#define NNODES   80000
#define IN_DIM   8
#define HID      128
#define HEADS    8
#define KH       16
#define NEDGE    1280000
#define NETOT    (NEDGE + NNODES)
#define NEGS     0.2f
#define EPSBN    1e-5f
#define BATCH    8
#define PERB     10000
#define NBLK     313            // ceil(80000/256)

__device__ __forceinline__ float lrelu(float v) { return v >= 0.f ? v : NEGS * v; }

// ---------- CSR build (dst and src), once per call ----------
__global__ void k_count2(const int* __restrict__ ei, int* __restrict__ cntD,
                         int* __restrict__ cntS) {
  int e = blockIdx.x * blockDim.x + threadIdx.x;
  if (e >= NEDGE) return;
  atomicAdd(&cntD[ei[NEDGE + e]], 1);
  atomicAdd(&cntS[ei[e]], 1);
}

__global__ void k_scan1(int* __restrict__ data, int* __restrict__ bsum) {
  __shared__ int tmp[256];
  int i = blockIdx.x * 256 + threadIdx.x;
  int v = (i < NNODES) ? data[i] : 0;
  tmp[threadIdx.x] = v;
  __syncthreads();
  for (int off = 1; off < 256; off <<= 1) {
    int t = (threadIdx.x >= off) ? tmp[threadIdx.x - off] : 0;
    __syncthreads();
    tmp[threadIdx.x] += t;
    __syncthreads();
  }
  if (i < NNODES) data[i] = tmp[threadIdx.x] - v;   // exclusive
  if (threadIdx.x == 255) bsum[blockIdx.x] = tmp[255];
}

__global__ void k_scan2(int* __restrict__ bsum, int* __restrict__ bex) {
  __shared__ int tmp[512];
  int v = (threadIdx.x < NBLK) ? bsum[threadIdx.x] : 0;
  tmp[threadIdx.x] = v;
  __syncthreads();
  for (int off = 1; off < 512; off <<= 1) {
    int t = (threadIdx.x >= off) ? tmp[threadIdx.x - off] : 0;
    __syncthreads();
    tmp[threadIdx.x] += t;
    __syncthreads();
  }
  if (threadIdx.x < NBLK) bex[threadIdx.x] = tmp[threadIdx.x] - v;
}

__global__ void k_scan3(int* __restrict__ data, const int* __restrict__ bex) {
  int i = blockIdx.x * 256 + threadIdx.x;
  if (i < NNODES) data[i] += bex[blockIdx.x];
  if (i == 0) data[NNODES] = NEDGE;
}

// fill both CSRs: src list stores the edge's DST node; dst list stores src only
__global__ void k_fill2(const int* __restrict__ ei, const int* __restrict__ rowptrD,
                        const int* __restrict__ rowptrS, int* __restrict__ fcD,
                        int* __restrict__ fcS, int* __restrict__ eD,
                        int* __restrict__ eSd) {
  int e = blockIdx.x * blockDim.x + threadIdx.x;
  if (e >= NEDGE) return;
  int s = ei[e];
  int d = ei[NEDGE + e];
  int posS = rowptrS[s] + atomicAdd(&fcS[s], 1);
  eSd[posS] = d;
  int posD = rowptrD[d] + atomicAdd(&fcD[d], 1);
  eD[posD] = s;
}

// ---------- layer-1 GEMM (K=8): W1 in registers; h fp16; fused att dots ----------
__global__ void k_gemm_in(const float* __restrict__ x, const float* __restrict__ W,
                          const float* __restrict__ att, __half* __restrict__ hh,
                          float* __restrict__ aL, float* __restrict__ aR) {
  int tid = blockIdx.x * blockDim.x + threadIdx.x;
  int tx = tid & 15;
  int c0 = tx * 8;
  int hd = tx >> 1;
  int k0 = (tx & 1) * 8;
  float4 wv[16];
#pragma unroll
  for (int j = 0; j < 8; j++) {
    wv[j * 2 + 0] = *(const float4*)(W + (size_t)(c0 + j) * IN_DIM);
    wv[j * 2 + 1] = *(const float4*)(W + (size_t)(c0 + j) * IN_DIM + 4);
  }
  float attL[8], attR[8];
#pragma unroll
  for (int j = 0; j < 8; j++) {
    attL[j] = att[hd * 2 * KH + k0 + j];
    attR[j] = att[hd * 2 * KH + KH + k0 + j];
  }
  int stride = (gridDim.x * blockDim.x) >> 4;
  for (int n = tid >> 4; n < NNODES; n += stride) {
    float4 x0 = *(const float4*)(x + (size_t)n * IN_DIM);
    float4 x1 = *(const float4*)(x + (size_t)n * IN_DIM + 4);
    float o[8];
#pragma unroll
    for (int j = 0; j < 8; j++) {
      float4 a = wv[j * 2], b = wv[j * 2 + 1];
      o[j] = x0.x*a.x + x0.y*a.y + x0.z*a.z + x0.w*a.w
           + x1.x*b.x + x1.y*b.y + x1.z*b.z + x1.w*b.w;
    }
    __half2* hp = (__half2*)(hh + (size_t)n * HID + c0);
    hp[0] = __floats2half2_rn(o[0], o[1]);
    hp[1] = __floats2half2_rn(o[2], o[3]);
    hp[2] = __floats2half2_rn(o[4], o[5]);
    hp[3] = __floats2half2_rn(o[6], o[7]);
    float sl = 0.f, sr = 0.f;
#pragma unroll
    for (int j = 0; j < 8; j++) { sl += o[j] * attL[j]; sr += o[j] * attR[j]; }
    sl += __shfl_xor(sl, 1, 64);
    sr += __shfl_xor(sr, 1, 64);
    if (!(tx & 1)) { aL[n * 8 + hd] = sl; aR[n * 8 + hd] = sr; }
  }
}

// ---------- 128x128 GEMM, fused input BN+lrelu, h fp16, fused att dots ----------
#define GB_NODES 128
__global__ __launch_bounds__(256, 2)
void k_gemm128_bn(const float* __restrict__ y, const float* __restrict__ scale,
                  const float* __restrict__ shift, const float* __restrict__ W,
                  const float* __restrict__ att, __half* __restrict__ hh,
                  float* __restrict__ aL, float* __restrict__ aR) {
  __shared__ float sw[HID][HID + 4];
  __shared__ float sscale[HID], sshift[HID];
  int tid = threadIdx.x;
  if (tid < HID) { sscale[tid] = scale[tid]; sshift[tid] = shift[tid]; }
  for (int idx = tid * 4; idx < HID * HID; idx += 256 * 4) {
    int c = idx >> 7, k = idx & 127;
    float4 w = *(const float4*)(W + (size_t)c * HID + k);
    sw[k + 0][c] = w.x; sw[k + 1][c] = w.y; sw[k + 2][c] = w.z; sw[k + 3][c] = w.w;
  }
  __syncthreads();
  int tx = tid & 15, ty = tid >> 4;
  int n0 = blockIdx.x * GB_NODES + ty * 8;
  int c0 = tx * 8;
  int hd = tx >> 1;
  int k0 = (tx & 1) * 8;
  float attL[8], attR[8];
#pragma unroll
  for (int j = 0; j < 8; j++) {
    attL[j] = att[hd * 2 * KH + k0 + j];
    attR[j] = att[hd * 2 * KH + KH + k0 + j];
  }
  float acc[8][8];
#pragma unroll
  for (int i = 0; i < 8; i++)
#pragma unroll
    for (int j = 0; j < 8; j++) acc[i][j] = 0.f;

  const float* xp = y + (size_t)n0 * HID;
  for (int kk = 0; kk < HID; kk += 4) {
    float4 sc = *(const float4*)&sscale[kk];
    float4 sh = *(const float4*)&sshift[kk];
    float4 xv[8];
#pragma unroll
    for (int i = 0; i < 8; i++) {
      float4 v = *(const float4*)(xp + (size_t)i * HID + kk);
      v.x = lrelu(v.x * sc.x + sh.x);
      v.y = lrelu(v.y * sc.y + sh.y);
      v.z = lrelu(v.z * sc.z + sh.z);
      v.w = lrelu(v.w * sc.w + sh.w);
      xv[i] = v;
    }
#pragma unroll
    for (int k4 = 0; k4 < 4; k4++) {
      float4 w0 = *(const float4*)&sw[kk + k4][c0];
      float4 w1 = *(const float4*)&sw[kk + k4][c0 + 4];
      float wj[8] = { w0.x, w0.y, w0.z, w0.w, w1.x, w1.y, w1.z, w1.w };
#pragma unroll
      for (int i = 0; i < 8; i++) {
        const float* xe = (const float*)&xv[i];
        float xs = xe[k4];
#pragma unroll
        for (int j = 0; j < 8; j++) acc[i][j] += xs * wj[j];
      }
    }
  }
#pragma unroll
  for (int i = 0; i < 8; i++) {
    __half2* hp = (__half2*)(hh + (size_t)(n0 + i) * HID + c0);
    hp[0] = __floats2half2_rn(acc[i][0], acc[i][1]);
    hp[1] = __floats2half2_rn(acc[i][2], acc[i][3]);
    hp[2] = __floats2half2_rn(acc[i][4], acc[i][5]);
    hp[3] = __floats2half2_rn(acc[i][6], acc[i][7]);
    float sl = 0.f, sr = 0.f;
#pragma unroll
    for (int j = 0; j < 8; j++) { sl += acc[i][j] * attL[j]; sr += acc[i][j] * attR[j]; }
    sl += __shfl_xor(sl, 1, 64);
    sr += __shfl_xor(sr, 1, 64);
    if (!(tx & 1)) { aL[(n0 + i) * 8 + hd] = sl; aR[(n0 + i) * 8 + hd] = sr; }
  }
}

// per (node, head): online softmax stats over out-edges; packs
// (aR, m, rinv, alpha_self) into float4 pk. No alpha array, single pass.
__global__ void k_src_softmax(const int* __restrict__ rowptrS, const int* __restrict__ eSd,
                              const float* __restrict__ aL, const float* __restrict__ aR,
                              float4* __restrict__ pk) {
  int t = blockIdx.x * blockDim.x + threadIdx.x;
  int n = t >> 3;
  if (n >= NNODES) return;
  int hd = t & 7;
  int sh = n * 8 + hd;
  float aRn = aR[sh];
  float aself_a = lrelu(aL[sh] + aRn);
  float m = aself_a, l = 1.f;
  int j0 = rowptrS[n], j1 = rowptrS[n + 1];
  for (int j = j0; j < j1; j++) {
    int d = eSd[j];
    float a = lrelu(aL[d * 8 + hd] + aRn);
    if (a > m) { l = l * __expf(m - a) + 1.f; m = a; }
    else       { l += __expf(a - m); }
  }
  float rinv = 1.f / (l + 1e-16f);
  pk[sh] = make_float4(aRn, m, rinv, __expf(aself_a - m) * rinv);
}

// gather aggregation via dst-CSR; 64 threads/node, 2 channels/thread (__half2)
__global__ __launch_bounds__(256)
void k_agg_gather(const int* __restrict__ rowptrD, const int* __restrict__ eD,
                  const float4* __restrict__ pk, const float* __restrict__ aL,
                  const __half2* __restrict__ hh2, const float2* __restrict__ bias2,
                  float* __restrict__ yout) {
  int node = blockIdx.x * 4 + (threadIdx.x >> 6);
  if (node >= NNODES) return;
  int c = threadIdx.x & 63;       // channel-pair index: channels 2c, 2c+1
  int hd = c >> 3;
  float aln = aL[node * 8 + hd];
  float4 pkn = pk[node * 8 + hd];
  float2 hs = __half22float2(hh2[(size_t)node * 64 + c]);
  float ax = pkn.w * hs.x, ay = pkn.w * hs.y;
  int j = rowptrD[node], j1 = rowptrD[node + 1];
  for (; j + 1 < j1; j += 2) {
    int s0 = eD[j], s1 = eD[j + 1];
    float4 q0 = pk[s0 * 8 + hd];
    float4 q1 = pk[s1 * 8 + hd];
    float2 v0 = __half22float2(hh2[(size_t)s0 * 64 + c]);
    float2 v1 = __half22float2(hh2[(size_t)s1 * 64 + c]);
    float al0 = __expf(lrelu(aln + q0.x) - q0.y) * q0.z;
    float al1 = __expf(lrelu(aln + q1.x) - q1.y) * q1.z;
    ax += al0 * v0.x + al1 * v1.x;
    ay += al0 * v0.y + al1 * v1.y;
  }
  if (j < j1) {
    int s0 = eD[j];
    float4 q0 = pk[s0 * 8 + hd];
    float2 v0 = __half22float2(hh2[(size_t)s0 * 64 + c]);
    float al0 = __expf(lrelu(aln + q0.x) - q0.y) * q0.z;
    ax += al0 * v0.x;
    ay += al0 * v0.y;
  }
  float2 bb = bias2[c];
  float vx = ax + bb.x, vy = ay + bb.y;
  float2* yp = (float2*)(yout + (size_t)node * HID + c * 2);
  *yp = make_float2(vx > 0.f ? vx : 0.f, vy > 0.f ? vy : 0.f);
}

// BN statistics (read-only over y)
__global__ void k_bnstats(const float* __restrict__ y, double* __restrict__ bnsum,
                          double* __restrict__ bnsq) {
  int c = threadIdx.x;
  float s = 0.f, sq = 0.f;
  for (int n = blockIdx.x; n < NNODES; n += gridDim.x) {
    float v = y[(size_t)n * HID + c];
    s += v; sq += v * v;
  }
  atomicAdd(&bnsum[c], (double)s);
  atomicAdd(&bnsq[c], (double)sq);
}

__global__ void k_bnfinal(const double* __restrict__ bnsum, const double* __restrict__ bnsq,
                          const float* __restrict__ g, const float* __restrict__ be,
                          float* __restrict__ scale, float* __restrict__ shift) {
  int c = threadIdx.x;
  double mean = bnsum[c] / (double)NNODES;
  double var  = bnsq[c] / (double)NNODES - mean * mean;
  float rs = (float)(1.0 / sqrt(var + (double)EPSBN));
  float sc = g[c] * rs;
  scale[c] = sc;
  shift[c] = be[c] - (float)mean * sc;
}

// power-mean partial sums with fused BN+lrelu (layer-3 BN applied here)
__global__ void k_pmean_bn(const float* __restrict__ y, const float* __restrict__ scale,
                           const float* __restrict__ shift, const float* __restrict__ p_,
                           float* __restrict__ xgsum) {
  int b = blockIdx.y, c = threadIdx.x;
  float p = p_[0];
  float sc = scale[c], sh = shift[c];
  int rows_per = (PERB + gridDim.x - 1) / gridDim.x;
  int r0 = blockIdx.x * rows_per;
  int r1 = r0 + rows_per; if (r1 > PERB) r1 = PERB;
  float acc = 0.f;
  for (int i = r0; i < r1; i++) {
    float v = y[((size_t)b * PERB + i) * HID + c];
    v = lrelu(v * sc + sh);
    v = fminf(fmaxf(v, 0.f), 100.f);
    acc += powf(v, p);
  }
  atomicAdd(&xgsum[b * HID + c], acc);
}

__global__ void k_head(const float* __restrict__ xgsum, const float* __restrict__ p_,
                       const float* __restrict__ Wg, const float* __restrict__ bg,
                       float* __restrict__ out) {
  __shared__ float sxg[HID];
  __shared__ float red[HID];
  int b = blockIdx.x, c = threadIdx.x;
  float p = p_[0];
  float m = xgsum[b * HID + c] / (float)PERB;
  m = fminf(fmaxf(m, 0.f), 100.f);
  sxg[c] = powf(m, 1.0f / p);
  __syncthreads();
  float l0 = 0.f, l1 = 0.f;
  for (int j = 0; j < 2; j++) {
    red[c] = sxg[c] * Wg[j * HID + c];
    __syncthreads();
    for (int off = 64; off > 0; off >>= 1) {
      if (c < off) red[c] += red[c + off];
      __syncthreads();
    }
    if (c == 0) { if (j == 0) l0 = red[0] + bg[0]; else l1 = red[0] + bg[1]; }
    __syncthreads();
  }
  if (c == 0) {
    out[b * 2 + 0] = l0;
    out[b * 2 + 1] = l1;
    out[2 * BATCH + b] = (l1 > l0) ? 1.0f : 0.0f;
  }
}

extern "C" void kernel_launch(void* const* d_in, const int* in_sizes, int n_in,
                              void* d_out, int out_size, void* d_ws, size_t ws_size,
                              hipStream_t stream) {
  (void)in_sizes; (void)n_in; (void)out_size; (void)ws_size;
  const float* x    = (const float*)d_in[0];
  const int*   ei   = (const int*)d_in[1];
  const float* Wl[3]   = { (const float*)d_in[2],  (const float*)d_in[7],  (const float*)d_in[12] };
  const float* attl[3] = { (const float*)d_in[3],  (const float*)d_in[8],  (const float*)d_in[13] };
  const float* bl[3]   = { (const float*)d_in[4],  (const float*)d_in[9],  (const float*)d_in[14] };
  const float* gl[3]   = { (const float*)d_in[5],  (const float*)d_in[10], (const float*)d_in[15] };
  const float* bel[3]  = { (const float*)d_in[6],  (const float*)d_in[11], (const float*)d_in[16] };
  const float* p    = (const float*)d_in[17];
  const float* Wg   = (const float*)d_in[18];
  const float* bg   = (const float*)d_in[19];
  float* out = (float*)d_out;

  float* ws   = (float*)d_ws;
  __half* hh  = (__half*)ws;                         // N*128 halfs = N*64 floats
  float* agg  = ws + (size_t)NNODES * (HID / 2);     // N*128 floats (= y, pre-BN)
  float* aL   = agg + (size_t)NNODES * HID;          // N*8
  float* aR   = aL  + (size_t)NNODES * HEADS;        // N*8
  float4* pk  = (float4*)(aR + (size_t)NNODES * HEADS);  // N*8 float4 (16B-aligned offset)
  double* bnsum = (double*)(pk + (size_t)NNODES * HEADS);
  double* bnsq  = bnsum + HID;
  float* scale  = (float*)(bnsq + HID);
  float* shift  = scale + HID;
  float* xgsum  = shift + HID;                       // 8*128
  int* eD       = (int*)(xgsum + BATCH * HID);       // NEDGE (src per dst-ordered edge)
  int* eSd      = eD + NEDGE;                        // NEDGE (dst per src-ordered edge)
  int* rowptrD  = eSd + NEDGE;                       // N+1
  int* rowptrS  = rowptrD + (NNODES + 1);            // N+1
  int* fcD      = rowptrS + (NNODES + 1);            // N
  int* fcS      = fcD + NNODES;                      // N
  int* bsum     = fcS + NNODES;                      // NBLK
  int* bex      = bsum + NBLK;                       // NBLK

  // ---- build dst-CSR and src-CSR ----
  hipMemsetAsync(rowptrD, 0, sizeof(int) * (4 * NNODES + 2), stream);
  k_count2<<<(NEDGE + 255) / 256, 256, 0, stream>>>(ei, rowptrD, rowptrS);
  k_scan1<<<NBLK, 256, 0, stream>>>(rowptrD, bsum);
  k_scan2<<<1, 512, 0, stream>>>(bsum, bex);
  k_scan3<<<NBLK, 256, 0, stream>>>(rowptrD, bex);
  k_scan1<<<NBLK, 256, 0, stream>>>(rowptrS, bsum);
  k_scan2<<<1, 512, 0, stream>>>(bsum, bex);
  k_scan3<<<NBLK, 256, 0, stream>>>(rowptrS, bex);
  k_fill2<<<(NEDGE + 255) / 256, 256, 0, stream>>>(ei, rowptrD, rowptrS, fcD, fcS, eD, eSd);

  for (int layer = 0; layer < 3; layer++) {
    if (layer == 0)
      k_gemm_in<<<2048, 256, 0, stream>>>(x, Wl[0], attl[0], hh, aL, aR);
    else
      k_gemm128_bn<<<NNODES / GB_NODES, 256, 0, stream>>>(agg, scale, shift, Wl[layer],
                                                          attl[layer], hh, aL, aR);

    k_src_softmax<<<(NNODES * 8 + 255) / 256, 256, 0, stream>>>(rowptrS, eSd, aL, aR, pk);
    k_agg_gather<<<NNODES / 4, 256, 0, stream>>>(rowptrD, eD, pk, aL, (const __half2*)hh,
                                                 (const float2*)bl[layer], agg);

    hipMemsetAsync(bnsum, 0, sizeof(double) * HID * 2, stream);
    k_bnstats<<<1024, 128, 0, stream>>>(agg, bnsum, bnsq);
    k_bnfinal<<<1, 128, 0, stream>>>(bnsum, bnsq, gl[layer], bel[layer], scale, shift);
  }

  hipMemsetAsync(xgsum, 0, sizeof(float) * BATCH * HID, stream);
  k_pmean_bn<<<dim3(256, BATCH), 128, 0, stream>>>(agg, scale, shift, p, xgsum);
  k_head<<<BATCH, 128, 0, stream>>>(xgsum, p, Wg, bg, out);
}

// Round 13
// 1033.677 us; speedup vs baseline: 4.5844x; 1.0631x over previous
//
#include <hip/hip_runtime.h>
#include <hip/hip_fp16.h>
#include <math.h>

#define NNODES   80000
#define IN_DIM   8
#define HID      128
#define HEADS    8
#define KH       16
#define NEDGE    1280000
#define NETOT    (NEDGE + NNODES)
#define NEGS     0.2f
#define EPSBN    1e-5f
#define BATCH    8
#define PERB     10000
#define NBLK     313            // ceil(80000/256)

__device__ __forceinline__ float lrelu(float v) { return v >= 0.f ? v : NEGS * v; }

// ---------- CSR build (dst and src), once per call ----------
__global__ void k_count2(const int* __restrict__ ei, int* __restrict__ cntD,
                         int* __restrict__ cntS) {
  int e = blockIdx.x * blockDim.x + threadIdx.x;
  if (e >= NEDGE) return;
  atomicAdd(&cntD[ei[NEDGE + e]], 1);
  atomicAdd(&cntS[ei[e]], 1);
}

__global__ void k_scan1(int* __restrict__ data, int* __restrict__ bsum) {
  __shared__ int tmp[256];
  int i = blockIdx.x * 256 + threadIdx.x;
  int v = (i < NNODES) ? data[i] : 0;
  tmp[threadIdx.x] = v;
  __syncthreads();
  for (int off = 1; off < 256; off <<= 1) {
    int t = (threadIdx.x >= off) ? tmp[threadIdx.x - off] : 0;
    __syncthreads();
    tmp[threadIdx.x] += t;
    __syncthreads();
  }
  if (i < NNODES) data[i] = tmp[threadIdx.x] - v;   // exclusive
  if (threadIdx.x == 255) bsum[blockIdx.x] = tmp[255];
}

__global__ void k_scan2(int* __restrict__ bsum, int* __restrict__ bex) {
  __shared__ int tmp[512];
  int v = (threadIdx.x < NBLK) ? bsum[threadIdx.x] : 0;
  tmp[threadIdx.x] = v;
  __syncthreads();
  for (int off = 1; off < 512; off <<= 1) {
    int t = (threadIdx.x >= off) ? tmp[threadIdx.x - off] : 0;
    __syncthreads();
    tmp[threadIdx.x] += t;
    __syncthreads();
  }
  if (threadIdx.x < NBLK) bex[threadIdx.x] = tmp[threadIdx.x] - v;
}

__global__ void k_scan3(int* __restrict__ data, const int* __restrict__ bex) {
  int i = blockIdx.x * 256 + threadIdx.x;
  if (i < NNODES) data[i] += bex[blockIdx.x];
  if (i == 0) data[NNODES] = NEDGE;
}

// fill both CSRs: src list stores the edge's DST node; dst list stores src only
__global__ void k_fill2(const int* __restrict__ ei, const int* __restrict__ rowptrD,
                        const int* __restrict__ rowptrS, int* __restrict__ fcD,
                        int* __restrict__ fcS, int* __restrict__ eD,
                        int* __restrict__ eSd) {
  int e = blockIdx.x * blockDim.x + threadIdx.x;
  if (e >= NEDGE) return;
  int s = ei[e];
  int d = ei[NEDGE + e];
  int posS = rowptrS[s] + atomicAdd(&fcS[s], 1);
  eSd[posS] = d;
  int posD = rowptrD[d] + atomicAdd(&fcD[d], 1);
  eD[posD] = s;
}

// ---------- layer-1 GEMM (K=8): W1 in registers; h fp16; fused att dots ----------
__global__ void k_gemm_in(const float* __restrict__ x, const float* __restrict__ W,
                          const float* __restrict__ att, __half* __restrict__ hh,
                          float* __restrict__ aL, float* __restrict__ aR) {
  int tid = blockIdx.x * blockDim.x + threadIdx.x;
  int tx = tid & 15;
  int c0 = tx * 8;
  int hd = tx >> 1;
  int k0 = (tx & 1) * 8;
  float4 wv[16];
#pragma unroll
  for (int j = 0; j < 8; j++) {
    wv[j * 2 + 0] = *(const float4*)(W + (size_t)(c0 + j) * IN_DIM);
    wv[j * 2 + 1] = *(const float4*)(W + (size_t)(c0 + j) * IN_DIM + 4);
  }
  float attL[8], attR[8];
#pragma unroll
  for (int j = 0; j < 8; j++) {
    attL[j] = att[hd * 2 * KH + k0 + j];
    attR[j] = att[hd * 2 * KH + KH + k0 + j];
  }
  int stride = (gridDim.x * blockDim.x) >> 4;
  for (int n = tid >> 4; n < NNODES; n += stride) {
    float4 x0 = *(const float4*)(x + (size_t)n * IN_DIM);
    float4 x1 = *(const float4*)(x + (size_t)n * IN_DIM + 4);
    float o[8];
#pragma unroll
    for (int j = 0; j < 8; j++) {
      float4 a = wv[j * 2], b = wv[j * 2 + 1];
      o[j] = x0.x*a.x + x0.y*a.y + x0.z*a.z + x0.w*a.w
           + x1.x*b.x + x1.y*b.y + x1.z*b.z + x1.w*b.w;
    }
    __half2* hp = (__half2*)(hh + (size_t)n * HID + c0);
    hp[0] = __floats2half2_rn(o[0], o[1]);
    hp[1] = __floats2half2_rn(o[2], o[3]);
    hp[2] = __floats2half2_rn(o[4], o[5]);
    hp[3] = __floats2half2_rn(o[6], o[7]);
    float sl = 0.f, sr = 0.f;
#pragma unroll
    for (int j = 0; j < 8; j++) { sl += o[j] * attL[j]; sr += o[j] * attR[j]; }
    sl += __shfl_xor(sl, 1, 64);
    sr += __shfl_xor(sr, 1, 64);
    if (!(tx & 1)) { aL[n * 8 + hd] = sl; aR[n * 8 + hd] = sr; }
  }
}

// ---------- 128x128 GEMM, fused input BN+lrelu, h fp16, fused att dots ----------
#define GB_NODES 128
__global__ __launch_bounds__(256, 2)
void k_gemm128_bn(const float* __restrict__ y, const float* __restrict__ scale,
                  const float* __restrict__ shift, const float* __restrict__ W,
                  const float* __restrict__ att, __half* __restrict__ hh,
                  float* __restrict__ aL, float* __restrict__ aR) {
  __shared__ float sw[HID][HID + 4];
  __shared__ float sscale[HID], sshift[HID];
  int tid = threadIdx.x;
  if (tid < HID) { sscale[tid] = scale[tid]; sshift[tid] = shift[tid]; }
  for (int idx = tid * 4; idx < HID * HID; idx += 256 * 4) {
    int c = idx >> 7, k = idx & 127;
    float4 w = *(const float4*)(W + (size_t)c * HID + k);
    sw[k + 0][c] = w.x; sw[k + 1][c] = w.y; sw[k + 2][c] = w.z; sw[k + 3][c] = w.w;
  }
  __syncthreads();
  int tx = tid & 15, ty = tid >> 4;
  int n0 = blockIdx.x * GB_NODES + ty * 8;
  int c0 = tx * 8;
  int hd = tx >> 1;
  int k0 = (tx & 1) * 8;
  float attL[8], attR[8];
#pragma unroll
  for (int j = 0; j < 8; j++) {
    attL[j] = att[hd * 2 * KH + k0 + j];
    attR[j] = att[hd * 2 * KH + KH + k0 + j];
  }
  float acc[8][8];
#pragma unroll
  for (int i = 0; i < 8; i++)
#pragma unroll
    for (int j = 0; j < 8; j++) acc[i][j] = 0.f;

  const float* xp = y + (size_t)n0 * HID;
  for (int kk = 0; kk < HID; kk += 4) {
    float4 sc = *(const float4*)&sscale[kk];
    float4 sh = *(const float4*)&sshift[kk];
    float4 xv[8];
#pragma unroll
    for (int i = 0; i < 8; i++) {
      float4 v = *(const float4*)(xp + (size_t)i * HID + kk);
      v.x = lrelu(v.x * sc.x + sh.x);
      v.y = lrelu(v.y * sc.y + sh.y);
      v.z = lrelu(v.z * sc.z + sh.z);
      v.w = lrelu(v.w * sc.w + sh.w);
      xv[i] = v;
    }
#pragma unroll
    for (int k4 = 0; k4 < 4; k4++) {
      float4 w0 = *(const float4*)&sw[kk + k4][c0];
      float4 w1 = *(const float4*)&sw[kk + k4][c0 + 4];
      float wj[8] = { w0.x, w0.y, w0.z, w0.w, w1.x, w1.y, w1.z, w1.w };
#pragma unroll
      for (int i = 0; i < 8; i++) {
        const float* xe = (const float*)&xv[i];
        float xs = xe[k4];
#pragma unroll
        for (int j = 0; j < 8; j++) acc[i][j] += xs * wj[j];
      }
    }
  }
#pragma unroll
  for (int i = 0; i < 8; i++) {
    __half2* hp = (__half2*)(hh + (size_t)(n0 + i) * HID + c0);
    hp[0] = __floats2half2_rn(acc[i][0], acc[i][1]);
    hp[1] = __floats2half2_rn(acc[i][2], acc[i][3]);
    hp[2] = __floats2half2_rn(acc[i][4], acc[i][5]);
    hp[3] = __floats2half2_rn(acc[i][6], acc[i][7]);
    float sl = 0.f, sr = 0.f;
#pragma unroll
    for (int j = 0; j < 8; j++) { sl += acc[i][j] * attL[j]; sr += acc[i][j] * attR[j]; }
    sl += __shfl_xor(sl, 1, 64);
    sr += __shfl_xor(sr, 1, 64);
    if (!(tx & 1)) { aL[(n0 + i) * 8 + hd] = sl; aR[(n0 + i) * 8 + hd] = sr; }
  }
}

// per (node, head): online softmax stats over out-edges; packs
// (aR, m, rinv, alpha_self) into float4 pk. No alpha array, single pass.
__global__ void k_src_softmax(const int* __restrict__ rowptrS, const int* __restrict__ eSd,
                              const float* __restrict__ aL, const float* __restrict__ aR,
                              float4* __restrict__ pk) {
  int t = blockIdx.x * blockDim.x + threadIdx.x;
  int n = t >> 3;
  if (n >= NNODES) return;
  int hd = t & 7;
  int sh = n * 8 + hd;
  float aRn = aR[sh];
  float aself_a = lrelu(aL[sh] + aRn);
  float m = aself_a, l = 1.f;
  int j0 = rowptrS[n], j1 = rowptrS[n + 1];
  for (int j = j0; j < j1; j++) {
    int d = eSd[j];
    float a = lrelu(aL[d * 8 + hd] + aRn);
    if (a > m) { l = l * __expf(m - a) + 1.f; m = a; }
    else       { l += __expf(a - m); }
  }
  float rinv = 1.f / (l + 1e-16f);
  pk[sh] = make_float4(aRn, m, rinv, __expf(aself_a - m) * rinv);
}

// gather aggregation via dst-CSR; 32 threads/node, 4 channels/thread (8B half loads)
__global__ __launch_bounds__(256)
void k_agg_gather(const int* __restrict__ rowptrD, const int* __restrict__ eD,
                  const float4* __restrict__ pk, const float* __restrict__ aL,
                  const float2* __restrict__ hh4,   // 8B = 4 halfs
                  const float4* __restrict__ bias4,
                  float* __restrict__ yout) {
  int node = blockIdx.x * 8 + (threadIdx.x >> 5);
  if (node >= NNODES) return;
  int c = threadIdx.x & 31;       // channel group: channels 4c..4c+3
  int hd = c >> 2;                // 4 lanes per head share pk
  float aln = aL[node * 8 + hd];
  float4 pkn = pk[node * 8 + hd];
  float2 raw = hh4[(size_t)node * 32 + c];
  __half2 rl = *(__half2*)&raw.x, rh = *(__half2*)&raw.y;
  float2 f0 = __half22float2(rl), f1 = __half22float2(rh);
  float a0 = pkn.w * f0.x, a1 = pkn.w * f0.y, a2 = pkn.w * f1.x, a3 = pkn.w * f1.y;
  int j = rowptrD[node], j1 = rowptrD[node + 1];
  for (; j + 1 < j1; j += 2) {
    int s0 = eD[j], s1 = eD[j + 1];
    float4 q0 = pk[s0 * 8 + hd];
    float4 q1 = pk[s1 * 8 + hd];
    float2 r0 = hh4[(size_t)s0 * 32 + c];
    float2 r1 = hh4[(size_t)s1 * 32 + c];
    float al0 = __expf(lrelu(aln + q0.x) - q0.y) * q0.z;
    float al1 = __expf(lrelu(aln + q1.x) - q1.y) * q1.z;
    __half2 r0l = *(__half2*)&r0.x, r0h = *(__half2*)&r0.y;
    __half2 r1l = *(__half2*)&r1.x, r1h = *(__half2*)&r1.y;
    float2 g0 = __half22float2(r0l), g1 = __half22float2(r0h);
    float2 g2 = __half22float2(r1l), g3 = __half22float2(r1h);
    a0 += al0 * g0.x + al1 * g2.x;
    a1 += al0 * g0.y + al1 * g2.y;
    a2 += al0 * g1.x + al1 * g3.x;
    a3 += al0 * g1.y + al1 * g3.y;
  }
  if (j < j1) {
    int s0 = eD[j];
    float4 q0 = pk[s0 * 8 + hd];
    float2 r0 = hh4[(size_t)s0 * 32 + c];
    float al0 = __expf(lrelu(aln + q0.x) - q0.y) * q0.z;
    __half2 r0l = *(__half2*)&r0.x, r0h = *(__half2*)&r0.y;
    float2 g0 = __half22float2(r0l), g1 = __half22float2(r0h);
    a0 += al0 * g0.x; a1 += al0 * g0.y; a2 += al0 * g1.x; a3 += al0 * g1.y;
  }
  float4 bb = bias4[c];
  float4 v = make_float4(a0 + bb.x, a1 + bb.y, a2 + bb.z, a3 + bb.w);
  v.x = v.x > 0.f ? v.x : 0.f;
  v.y = v.y > 0.f ? v.y : 0.f;
  v.z = v.z > 0.f ? v.z : 0.f;
  v.w = v.w > 0.f ? v.w : 0.f;
  *(float4*)(yout + (size_t)node * HID + c * 4) = v;
}

// BN statistics (read-only over y)
__global__ void k_bnstats(const float* __restrict__ y, double* __restrict__ bnsum,
                          double* __restrict__ bnsq) {
  int c = threadIdx.x;
  float s = 0.f, sq = 0.f;
  for (int n = blockIdx.x; n < NNODES; n += gridDim.x) {
    float v = y[(size_t)n * HID + c];
    s += v; sq += v * v;
  }
  atomicAdd(&bnsum[c], (double)s);
  atomicAdd(&bnsq[c], (double)sq);
}

__global__ void k_bnfinal(const double* __restrict__ bnsum, const double* __restrict__ bnsq,
                          const float* __restrict__ g, const float* __restrict__ be,
                          float* __restrict__ scale, float* __restrict__ shift) {
  int c = threadIdx.x;
  double mean = bnsum[c] / (double)NNODES;
  double var  = bnsq[c] / (double)NNODES - mean * mean;
  float rs = (float)(1.0 / sqrt(var + (double)EPSBN));
  float sc = g[c] * rs;
  scale[c] = sc;
  shift[c] = be[c] - (float)mean * sc;
}

// power-mean partial sums with fused BN+lrelu (layer-3 BN applied here)
__global__ void k_pmean_bn(const float* __restrict__ y, const float* __restrict__ scale,
                           const float* __restrict__ shift, const float* __restrict__ p_,
                           float* __restrict__ xgsum) {
  int b = blockIdx.y, c = threadIdx.x;
  float p = p_[0];
  float sc = scale[c], sh = shift[c];
  int rows_per = (PERB + gridDim.x - 1) / gridDim.x;
  int r0 = blockIdx.x * rows_per;
  int r1 = r0 + rows_per; if (r1 > PERB) r1 = PERB;
  float acc = 0.f;
  for (int i = r0; i < r1; i++) {
    float v = y[((size_t)b * PERB + i) * HID + c];
    v = lrelu(v * sc + sh);
    v = fminf(fmaxf(v, 0.f), 100.f);
    acc += powf(v, p);
  }
  atomicAdd(&xgsum[b * HID + c], acc);
}

__global__ void k_head(const float* __restrict__ xgsum, const float* __restrict__ p_,
                       const float* __restrict__ Wg, const float* __restrict__ bg,
                       float* __restrict__ out) {
  __shared__ float sxg[HID];
  __shared__ float red[HID];
  int b = blockIdx.x, c = threadIdx.x;
  float p = p_[0];
  float m = xgsum[b * HID + c] / (float)PERB;
  m = fminf(fmaxf(m, 0.f), 100.f);
  sxg[c] = powf(m, 1.0f / p);
  __syncthreads();
  float l0 = 0.f, l1 = 0.f;
  for (int j = 0; j < 2; j++) {
    red[c] = sxg[c] * Wg[j * HID + c];
    __syncthreads();
    for (int off = 64; off > 0; off >>= 1) {
      if (c < off) red[c] += red[c + off];
      __syncthreads();
    }
    if (c == 0) { if (j == 0) l0 = red[0] + bg[0]; else l1 = red[0] + bg[1]; }
    __syncthreads();
  }
  if (c == 0) {
    out[b * 2 + 0] = l0;
    out[b * 2 + 1] = l1;
    out[2 * BATCH + b] = (l1 > l0) ? 1.0f : 0.0f;
  }
}

extern "C" void kernel_launch(void* const* d_in, const int* in_sizes, int n_in,
                              void* d_out, int out_size, void* d_ws, size_t ws_size,
                              hipStream_t stream) {
  (void)in_sizes; (void)n_in; (void)out_size; (void)ws_size;
  const float* x    = (const float*)d_in[0];
  const int*   ei   = (const int*)d_in[1];
  const float* Wl[3]   = { (const float*)d_in[2],  (const float*)d_in[7],  (const float*)d_in[12] };
  const float* attl[3] = { (const float*)d_in[3],  (const float*)d_in[8],  (const float*)d_in[13] };
  const float* bl[3]   = { (const float*)d_in[4],  (const float*)d_in[9],  (const float*)d_in[14] };
  const float* gl[3]   = { (const float*)d_in[5],  (const float*)d_in[10], (const float*)d_in[15] };
  const float* bel[3]  = { (const float*)d_in[6],  (const float*)d_in[11], (const float*)d_in[16] };
  const float* p    = (const float*)d_in[17];
  const float* Wg   = (const float*)d_in[18];
  const float* bg   = (const float*)d_in[19];
  float* out = (float*)d_out;

  float* ws   = (float*)d_ws;
  __half* hh  = (__half*)ws;                         // N*128 halfs = N*64 floats
  float* agg  = ws + (size_t)NNODES * (HID / 2);     // N*128 floats (= y, pre-BN)
  float* aL   = agg + (size_t)NNODES * HID;          // N*8
  float* aR   = aL  + (size_t)NNODES * HEADS;        // N*8
  float4* pk  = (float4*)(aR + (size_t)NNODES * HEADS);  // N*8 float4 (16B-aligned offset)
  double* bnsum = (double*)(pk + (size_t)NNODES * HEADS);
  double* bnsq  = bnsum + HID;
  float* scale  = (float*)(bnsq + HID);
  float* shift  = scale + HID;
  float* xgsum  = shift + HID;                       // 8*128
  int* eD       = (int*)(xgsum + BATCH * HID);       // NEDGE (src per dst-ordered edge)
  int* eSd      = eD + NEDGE;                        // NEDGE (dst per src-ordered edge)
  int* rowptrD  = eSd + NEDGE;                       // N+1
  int* rowptrS  = rowptrD + (NNODES + 1);            // N+1
  int* fcD      = rowptrS + (NNODES + 1);            // N
  int* fcS      = fcD + NNODES;                      // N
  int* bsum     = fcS + NNODES;                      // NBLK
  int* bex      = bsum + NBLK;                       // NBLK

  // ---- build dst-CSR and src-CSR ----
  hipMemsetAsync(rowptrD, 0, sizeof(int) * (4 * NNODES + 2), stream);
  k_count2<<<(NEDGE + 255) / 256, 256, 0, stream>>>(ei, rowptrD, rowptrS);
  k_scan1<<<NBLK, 256, 0, stream>>>(rowptrD, bsum);
  k_scan2<<<1, 512, 0, stream>>>(bsum, bex);
  k_scan3<<<NBLK, 256, 0, stream>>>(rowptrD, bex);
  k_scan1<<<NBLK, 256, 0, stream>>>(rowptrS, bsum);
  k_scan2<<<1, 512, 0, stream>>>(bsum, bex);
  k_scan3<<<NBLK, 256, 0, stream>>>(rowptrS, bex);
  k_fill2<<<(NEDGE + 255) / 256, 256, 0, stream>>>(ei, rowptrD, rowptrS, fcD, fcS, eD, eSd);

  for (int layer = 0; layer < 3; layer++) {
    if (layer == 0)
      k_gemm_in<<<2048, 256, 0, stream>>>(x, Wl[0], attl[0], hh, aL, aR);
    else
      k_gemm128_bn<<<NNODES / GB_NODES, 256, 0, stream>>>(agg, scale, shift, Wl[layer],
                                                          attl[layer], hh, aL, aR);

    k_src_softmax<<<(NNODES * 8 + 255) / 256, 256, 0, stream>>>(rowptrS, eSd, aL, aR, pk);
    k_agg_gather<<<NNODES / 8, 256, 0, stream>>>(rowptrD, eD, pk, aL, (const float2*)hh,
                                                 (const float4*)bl[layer], agg);

    hipMemsetAsync(bnsum, 0, sizeof(double) * HID * 2, stream);
    k_bnstats<<<1024, 128, 0, stream>>>(agg, bnsum, bnsq);
    k_bnfinal<<<1, 128, 0, stream>>>(bnsum, bnsq, gl[layer], bel[layer], scale, shift);
  }

  hipMemsetAsync(xgsum, 0, sizeof(float) * BATCH * HID, stream);
  k_pmean_bn<<<dim3(256, BATCH), 128, 0, stream>>>(agg, scale, shift, p, xgsum);
  k_head<<<BATCH, 128, 0, stream>>>(xgsum, p, Wg, bg, out);
}

// Round 14
// 1008.308 us; speedup vs baseline: 4.6998x; 1.0252x over previous
//
#include <hip/hip_runtime.h>
#include <hip/hip_fp16.h>
#include <math.h>

#define NNODES   80000
#define IN_DIM   8
#define HID      128
#define HEADS    8
#define KH       16
#define NEDGE    1280000
#define NETOT    (NEDGE + NNODES)
#define NEGS     0.2f
#define EPSBN    1e-5f
#define BATCH    8
#define PERB     10000

__device__ __forceinline__ float lrelu(float v) { return v >= 0.f ? v : NEGS * v; }

// ---------- linked-list graph build (one pass, no scans, coalesced payloads) ----------
// headD[d] -> most recent edge with dst=d; next2D[e] = {next edge, src}
// headS[s] -> most recent edge with src=s; next2S[e] = {next edge, dst}
__global__ void k_link(const int* __restrict__ ei, int* __restrict__ headD,
                       int* __restrict__ headS, int2* __restrict__ next2D,
                       int2* __restrict__ next2S) {
  int e = blockIdx.x * blockDim.x + threadIdx.x;
  if (e >= NEDGE) return;
  int s = ei[e];
  int d = ei[NEDGE + e];
  int hD = atomicExch(&headD[d], e);
  next2D[e] = make_int2(hD, s);       // coalesced 8B store
  int hS = atomicExch(&headS[s], e);
  next2S[e] = make_int2(hS, d);       // coalesced 8B store
}

// ---------- layer-1 GEMM (K=8): W1 in registers; h fp16; fused att dots ----------
__global__ void k_gemm_in(const float* __restrict__ x, const float* __restrict__ W,
                          const float* __restrict__ att, __half* __restrict__ hh,
                          float* __restrict__ aL, float* __restrict__ aR) {
  int tid = blockIdx.x * blockDim.x + threadIdx.x;
  int tx = tid & 15;
  int c0 = tx * 8;
  int hd = tx >> 1;
  int k0 = (tx & 1) * 8;
  float4 wv[16];
#pragma unroll
  for (int j = 0; j < 8; j++) {
    wv[j * 2 + 0] = *(const float4*)(W + (size_t)(c0 + j) * IN_DIM);
    wv[j * 2 + 1] = *(const float4*)(W + (size_t)(c0 + j) * IN_DIM + 4);
  }
  float attL[8], attR[8];
#pragma unroll
  for (int j = 0; j < 8; j++) {
    attL[j] = att[hd * 2 * KH + k0 + j];
    attR[j] = att[hd * 2 * KH + KH + k0 + j];
  }
  int stride = (gridDim.x * blockDim.x) >> 4;
  for (int n = tid >> 4; n < NNODES; n += stride) {
    float4 x0 = *(const float4*)(x + (size_t)n * IN_DIM);
    float4 x1 = *(const float4*)(x + (size_t)n * IN_DIM + 4);
    float o[8];
#pragma unroll
    for (int j = 0; j < 8; j++) {
      float4 a = wv[j * 2], b = wv[j * 2 + 1];
      o[j] = x0.x*a.x + x0.y*a.y + x0.z*a.z + x0.w*a.w
           + x1.x*b.x + x1.y*b.y + x1.z*b.z + x1.w*b.w;
    }
    __half2* hp = (__half2*)(hh + (size_t)n * HID + c0);
    hp[0] = __floats2half2_rn(o[0], o[1]);
    hp[1] = __floats2half2_rn(o[2], o[3]);
    hp[2] = __floats2half2_rn(o[4], o[5]);
    hp[3] = __floats2half2_rn(o[6], o[7]);
    float sl = 0.f, sr = 0.f;
#pragma unroll
    for (int j = 0; j < 8; j++) { sl += o[j] * attL[j]; sr += o[j] * attR[j]; }
    sl += __shfl_xor(sl, 1, 64);
    sr += __shfl_xor(sr, 1, 64);
    if (!(tx & 1)) { aL[n * 8 + hd] = sl; aR[n * 8 + hd] = sr; }
  }
}

// ---------- 128x128 GEMM, fused input BN+lrelu, h fp16, fused att dots ----------
#define GB_NODES 128
__global__ __launch_bounds__(256, 2)
void k_gemm128_bn(const float* __restrict__ y, const float* __restrict__ scale,
                  const float* __restrict__ shift, const float* __restrict__ W,
                  const float* __restrict__ att, __half* __restrict__ hh,
                  float* __restrict__ aL, float* __restrict__ aR) {
  __shared__ float sw[HID][HID + 4];
  __shared__ float sscale[HID], sshift[HID];
  int tid = threadIdx.x;
  if (tid < HID) { sscale[tid] = scale[tid]; sshift[tid] = shift[tid]; }
  for (int idx = tid * 4; idx < HID * HID; idx += 256 * 4) {
    int c = idx >> 7, k = idx & 127;
    float4 w = *(const float4*)(W + (size_t)c * HID + k);
    sw[k + 0][c] = w.x; sw[k + 1][c] = w.y; sw[k + 2][c] = w.z; sw[k + 3][c] = w.w;
  }
  __syncthreads();
  int tx = tid & 15, ty = tid >> 4;
  int n0 = blockIdx.x * GB_NODES + ty * 8;
  int c0 = tx * 8;
  int hd = tx >> 1;
  int k0 = (tx & 1) * 8;
  float attL[8], attR[8];
#pragma unroll
  for (int j = 0; j < 8; j++) {
    attL[j] = att[hd * 2 * KH + k0 + j];
    attR[j] = att[hd * 2 * KH + KH + k0 + j];
  }
  float acc[8][8];
#pragma unroll
  for (int i = 0; i < 8; i++)
#pragma unroll
    for (int j = 0; j < 8; j++) acc[i][j] = 0.f;

  const float* xp = y + (size_t)n0 * HID;
  for (int kk = 0; kk < HID; kk += 4) {
    float4 sc = *(const float4*)&sscale[kk];
    float4 sh = *(const float4*)&sshift[kk];
    float4 xv[8];
#pragma unroll
    for (int i = 0; i < 8; i++) {
      float4 v = *(const float4*)(xp + (size_t)i * HID + kk);
      v.x = lrelu(v.x * sc.x + sh.x);
      v.y = lrelu(v.y * sc.y + sh.y);
      v.z = lrelu(v.z * sc.z + sh.z);
      v.w = lrelu(v.w * sc.w + sh.w);
      xv[i] = v;
    }
#pragma unroll
    for (int k4 = 0; k4 < 4; k4++) {
      float4 w0 = *(const float4*)&sw[kk + k4][c0];
      float4 w1 = *(const float4*)&sw[kk + k4][c0 + 4];
      float wj[8] = { w0.x, w0.y, w0.z, w0.w, w1.x, w1.y, w1.z, w1.w };
#pragma unroll
      for (int i = 0; i < 8; i++) {
        const float* xe = (const float*)&xv[i];
        float xs = xe[k4];
#pragma unroll
        for (int j = 0; j < 8; j++) acc[i][j] += xs * wj[j];
      }
    }
  }
#pragma unroll
  for (int i = 0; i < 8; i++) {
    __half2* hp = (__half2*)(hh + (size_t)(n0 + i) * HID + c0);
    hp[0] = __floats2half2_rn(acc[i][0], acc[i][1]);
    hp[1] = __floats2half2_rn(acc[i][2], acc[i][3]);
    hp[2] = __floats2half2_rn(acc[i][4], acc[i][5]);
    hp[3] = __floats2half2_rn(acc[i][6], acc[i][7]);
    float sl = 0.f, sr = 0.f;
#pragma unroll
    for (int j = 0; j < 8; j++) { sl += acc[i][j] * attL[j]; sr += acc[i][j] * attR[j]; }
    sl += __shfl_xor(sl, 1, 64);
    sr += __shfl_xor(sr, 1, 64);
    if (!(tx & 1)) { aL[(n0 + i) * 8 + hd] = sl; aR[(n0 + i) * 8 + hd] = sr; }
  }
}

// per (node, head): online softmax stats over the src-chain; packs
// (aR, m, rinv, alpha_self) into float4 pk.
__global__ void k_src_softmax(const int* __restrict__ headS, const int2* __restrict__ next2S,
                              const float* __restrict__ aL, const float* __restrict__ aR,
                              float4* __restrict__ pk) {
  int t = blockIdx.x * blockDim.x + threadIdx.x;
  int n = t >> 3;
  if (n >= NNODES) return;
  int hd = t & 7;
  int sh = n * 8 + hd;
  float aRn = aR[sh];
  float aself_a = lrelu(aL[sh] + aRn);
  float m = aself_a, l = 1.f;
  int e = headS[n];
  while (e >= 0) {
    int2 pr = next2S[e];              // {next, dst} — broadcast across the 8 lanes
    float a = lrelu(aL[pr.y * 8 + hd] + aRn);
    if (a > m) { l = l * __expf(m - a) + 1.f; m = a; }
    else       { l += __expf(a - m); }
    e = pr.x;
  }
  float rinv = 1.f / (l + 1e-16f);
  pk[sh] = make_float4(aRn, m, rinv, __expf(aself_a - m) * rinv);
}

// gather aggregation via dst-chain; 32 threads/node, 4 channels/thread
__global__ __launch_bounds__(256)
void k_agg_gather(const int* __restrict__ headD, const int2* __restrict__ next2D,
                  const float4* __restrict__ pk, const float* __restrict__ aL,
                  const float2* __restrict__ hh4,   // 8B = 4 halfs
                  const float4* __restrict__ bias4,
                  float* __restrict__ yout) {
  int node = blockIdx.x * 8 + (threadIdx.x >> 5);
  if (node >= NNODES) return;
  int c = threadIdx.x & 31;       // channel group: channels 4c..4c+3
  int hd = c >> 2;                // 4 lanes per head share pk
  float aln = aL[node * 8 + hd];
  float4 pkn = pk[node * 8 + hd];
  float2 raw = hh4[(size_t)node * 32 + c];
  __half2 rl = *(__half2*)&raw.x, rh = *(__half2*)&raw.y;
  float2 f0 = __half22float2(rl), f1 = __half22float2(rh);
  float a0 = pkn.w * f0.x, a1 = pkn.w * f0.y, a2 = pkn.w * f1.x, a3 = pkn.w * f1.y;
  int e = headD[node];
  while (e >= 0) {
    int2 pr = next2D[e];            // {next, src} — broadcast across the 32 lanes
    int s0 = pr.y;
    float4 q0 = pk[s0 * 8 + hd];
    float2 r0 = hh4[(size_t)s0 * 32 + c];
    float al0 = __expf(lrelu(aln + q0.x) - q0.y) * q0.z;
    __half2 r0l = *(__half2*)&r0.x, r0h = *(__half2*)&r0.y;
    float2 g0 = __half22float2(r0l), g1 = __half22float2(r0h);
    a0 += al0 * g0.x; a1 += al0 * g0.y; a2 += al0 * g1.x; a3 += al0 * g1.y;
    e = pr.x;
  }
  float4 bb = bias4[c];
  float4 v = make_float4(a0 + bb.x, a1 + bb.y, a2 + bb.z, a3 + bb.w);
  v.x = v.x > 0.f ? v.x : 0.f;
  v.y = v.y > 0.f ? v.y : 0.f;
  v.z = v.z > 0.f ? v.z : 0.f;
  v.w = v.w > 0.f ? v.w : 0.f;
  *(float4*)(yout + (size_t)node * HID + c * 4) = v;
}

// BN statistics (read-only over y)
__global__ void k_bnstats(const float* __restrict__ y, double* __restrict__ bnsum,
                          double* __restrict__ bnsq) {
  int c = threadIdx.x;
  float s = 0.f, sq = 0.f;
  for (int n = blockIdx.x; n < NNODES; n += gridDim.x) {
    float v = y[(size_t)n * HID + c];
    s += v; sq += v * v;
  }
  atomicAdd(&bnsum[c], (double)s);
  atomicAdd(&bnsq[c], (double)sq);
}

__global__ void k_bnfinal(const double* __restrict__ bnsum, const double* __restrict__ bnsq,
                          const float* __restrict__ g, const float* __restrict__ be,
                          float* __restrict__ scale, float* __restrict__ shift) {
  int c = threadIdx.x;
  double mean = bnsum[c] / (double)NNODES;
  double var  = bnsq[c] / (double)NNODES - mean * mean;
  float rs = (float)(1.0 / sqrt(var + (double)EPSBN));
  float sc = g[c] * rs;
  scale[c] = sc;
  shift[c] = be[c] - (float)mean * sc;
}

// power-mean partial sums with fused BN+lrelu (layer-3 BN applied here)
__global__ void k_pmean_bn(const float* __restrict__ y, const float* __restrict__ scale,
                           const float* __restrict__ shift, const float* __restrict__ p_,
                           float* __restrict__ xgsum) {
  int b = blockIdx.y, c = threadIdx.x;
  float p = p_[0];
  float sc = scale[c], sh = shift[c];
  int rows_per = (PERB + gridDim.x - 1) / gridDim.x;
  int r0 = blockIdx.x * rows_per;
  int r1 = r0 + rows_per; if (r1 > PERB) r1 = PERB;
  float acc = 0.f;
  for (int i = r0; i < r1; i++) {
    float v = y[((size_t)b * PERB + i) * HID + c];
    v = lrelu(v * sc + sh);
    v = fminf(fmaxf(v, 0.f), 100.f);
    acc += powf(v, p);
  }
  atomicAdd(&xgsum[b * HID + c], acc);
}

__global__ void k_head(const float* __restrict__ xgsum, const float* __restrict__ p_,
                       const float* __restrict__ Wg, const float* __restrict__ bg,
                       float* __restrict__ out) {
  __shared__ float sxg[HID];
  __shared__ float red[HID];
  int b = blockIdx.x, c = threadIdx.x;
  float p = p_[0];
  float m = xgsum[b * HID + c] / (float)PERB;
  m = fminf(fmaxf(m, 0.f), 100.f);
  sxg[c] = powf(m, 1.0f / p);
  __syncthreads();
  float l0 = 0.f, l1 = 0.f;
  for (int j = 0; j < 2; j++) {
    red[c] = sxg[c] * Wg[j * HID + c];
    __syncthreads();
    for (int off = 64; off > 0; off >>= 1) {
      if (c < off) red[c] += red[c + off];
      __syncthreads();
    }
    if (c == 0) { if (j == 0) l0 = red[0] + bg[0]; else l1 = red[0] + bg[1]; }
    __syncthreads();
  }
  if (c == 0) {
    out[b * 2 + 0] = l0;
    out[b * 2 + 1] = l1;
    out[2 * BATCH + b] = (l1 > l0) ? 1.0f : 0.0f;
  }
}

extern "C" void kernel_launch(void* const* d_in, const int* in_sizes, int n_in,
                              void* d_out, int out_size, void* d_ws, size_t ws_size,
                              hipStream_t stream) {
  (void)in_sizes; (void)n_in; (void)out_size; (void)ws_size;
  const float* x    = (const float*)d_in[0];
  const int*   ei   = (const int*)d_in[1];
  const float* Wl[3]   = { (const float*)d_in[2],  (const float*)d_in[7],  (const float*)d_in[12] };
  const float* attl[3] = { (const float*)d_in[3],  (const float*)d_in[8],  (const float*)d_in[13] };
  const float* bl[3]   = { (const float*)d_in[4],  (const float*)d_in[9],  (const float*)d_in[14] };
  const float* gl[3]   = { (const float*)d_in[5],  (const float*)d_in[10], (const float*)d_in[15] };
  const float* bel[3]  = { (const float*)d_in[6],  (const float*)d_in[11], (const float*)d_in[16] };
  const float* p    = (const float*)d_in[17];
  const float* Wg   = (const float*)d_in[18];
  const float* bg   = (const float*)d_in[19];
  float* out = (float*)d_out;

  float* ws   = (float*)d_ws;
  __half* hh  = (__half*)ws;                         // N*128 halfs = N*64 floats
  float* agg  = ws + (size_t)NNODES * (HID / 2);     // N*128 floats (= y, pre-BN)
  float* aL   = agg + (size_t)NNODES * HID;          // N*8
  float* aR   = aL  + (size_t)NNODES * HEADS;        // N*8
  float4* pk  = (float4*)(aR + (size_t)NNODES * HEADS);  // N*8 float4 (16B-aligned offset)
  double* bnsum = (double*)(pk + (size_t)NNODES * HEADS);
  double* bnsq  = bnsum + HID;
  float* scale  = (float*)(bnsq + HID);
  float* shift  = scale + HID;
  float* xgsum  = shift + HID;                       // 8*128
  int2* next2D  = (int2*)(xgsum + BATCH * HID);      // NEDGE {next, src}
  int2* next2S  = next2D + NEDGE;                    // NEDGE {next, dst}
  int* headD    = (int*)(next2S + NEDGE);            // N
  int* headS    = headD + NNODES;                    // N

  // ---- build linked-list adjacency (both directions), one pass ----
  hipMemsetAsync(headD, 0xFF, sizeof(int) * 2 * NNODES, stream);   // -1
  k_link<<<(NEDGE + 255) / 256, 256, 0, stream>>>(ei, headD, headS, next2D, next2S);

  for (int layer = 0; layer < 3; layer++) {
    if (layer == 0)
      k_gemm_in<<<2048, 256, 0, stream>>>(x, Wl[0], attl[0], hh, aL, aR);
    else
      k_gemm128_bn<<<NNODES / GB_NODES, 256, 0, stream>>>(agg, scale, shift, Wl[layer],
                                                          attl[layer], hh, aL, aR);

    k_src_softmax<<<(NNODES * 8 + 255) / 256, 256, 0, stream>>>(headS, next2S, aL, aR, pk);
    k_agg_gather<<<NNODES / 8, 256, 0, stream>>>(headD, next2D, pk, aL, (const float2*)hh,
                                                 (const float4*)bl[layer], agg);

    hipMemsetAsync(bnsum, 0, sizeof(double) * HID * 2, stream);
    k_bnstats<<<1024, 128, 0, stream>>>(agg, bnsum, bnsq);
    k_bnfinal<<<1, 128, 0, stream>>>(bnsum, bnsq, gl[layer], bel[layer], scale, shift);
  }

  hipMemsetAsync(xgsum, 0, sizeof(float) * BATCH * HID, stream);
  k_pmean_bn<<<dim3(256, BATCH), 128, 0, stream>>>(agg, scale, shift, p, xgsum);
  k_head<<<BATCH, 128, 0, stream>>>(xgsum, p, Wg, bg, out);
}

// Round 15
// 782.370 us; speedup vs baseline: 6.0570x; 1.2888x over previous
//
#include <hip/hip_runtime.h>
#include <hip/hip_fp16.h>
#include <math.h>

#define NNODES   80000
#define IN_DIM   8
#define HID      128
#define HEADS    8
#define KH       16
#define NEDGE    1280000
#define NEGS     0.2f
#define EPSBN    1e-5f
#define BATCH    8
#define PERB     10000
#define NBINS    8
#define GGRID    2048

__device__ __forceinline__ float lrelu(float v) { return v >= 0.f ? v : NEGS * v; }

// ---------- linked-list graph build (one pass, coalesced payloads) ----------
__global__ void k_link(const int* __restrict__ ei, int* __restrict__ headD,
                       int* __restrict__ headS, int2* __restrict__ next2D,
                       int2* __restrict__ next2S) {
  int e = blockIdx.x * blockDim.x + threadIdx.x;
  if (e >= NEDGE) return;
  int s = ei[e];
  int d = ei[NEDGE + e];
  int hD = atomicExch(&headD[d], e);
  next2D[e] = make_int2(hD, s);
  int hS = atomicExch(&headS[s], e);
  next2S[e] = make_int2(hS, d);
}

// flatten chains to padded per-node arrays (walked ONCE per call)
__global__ void k_flatten(const int* __restrict__ headD, const int2* __restrict__ next2D,
                          const int* __restrict__ headS, const int2* __restrict__ next2S,
                          int* __restrict__ flatD, int* __restrict__ degD,
                          int* __restrict__ flatS, int* __restrict__ degS) {
  int t = blockIdx.x * blockDim.x + threadIdx.x;
  if (t < NNODES) {
    int n = t;
    int* fb = flatD + ((size_t)n << 6);
    int e = headD[n], i = 0;
    while (e >= 0 && i < 64) { int2 pr = next2D[e]; fb[i++] = pr.y; e = pr.x; }
    degD[n] = i;
  } else if (t < 2 * NNODES) {
    int n = t - NNODES;
    int* fb = flatS + ((size_t)n << 6);
    int e = headS[n], i = 0;
    while (e >= 0 && i < 64) { int2 pr = next2S[e]; fb[i++] = pr.y; e = pr.x; }
    degS[n] = i;
  }
}

// ---------- layer-1 GEMM (K=8): W1 in registers; h fp16; fused att dots ----------
__global__ void k_gemm_in(const float* __restrict__ x, const float* __restrict__ W,
                          const float* __restrict__ att, __half* __restrict__ hh,
                          float* __restrict__ aL, float* __restrict__ aR) {
  int tid = blockIdx.x * blockDim.x + threadIdx.x;
  int tx = tid & 15;
  int c0 = tx * 8;
  int hd = tx >> 1;
  int k0 = (tx & 1) * 8;
  float4 wv[16];
#pragma unroll
  for (int j = 0; j < 8; j++) {
    wv[j * 2 + 0] = *(const float4*)(W + (size_t)(c0 + j) * IN_DIM);
    wv[j * 2 + 1] = *(const float4*)(W + (size_t)(c0 + j) * IN_DIM + 4);
  }
  float attL[8], attR[8];
#pragma unroll
  for (int j = 0; j < 8; j++) {
    attL[j] = att[hd * 2 * KH + k0 + j];
    attR[j] = att[hd * 2 * KH + KH + k0 + j];
  }
  int stride = (gridDim.x * blockDim.x) >> 4;
  for (int n = tid >> 4; n < NNODES; n += stride) {
    float4 x0 = *(const float4*)(x + (size_t)n * IN_DIM);
    float4 x1 = *(const float4*)(x + (size_t)n * IN_DIM + 4);
    float o[8];
#pragma unroll
    for (int j = 0; j < 8; j++) {
      float4 a = wv[j * 2], b = wv[j * 2 + 1];
      o[j] = x0.x*a.x + x0.y*a.y + x0.z*a.z + x0.w*a.w
           + x1.x*b.x + x1.y*b.y + x1.z*b.z + x1.w*b.w;
    }
    __half2* hp = (__half2*)(hh + (size_t)n * HID + c0);
    hp[0] = __floats2half2_rn(o[0], o[1]);
    hp[1] = __floats2half2_rn(o[2], o[3]);
    hp[2] = __floats2half2_rn(o[4], o[5]);
    hp[3] = __floats2half2_rn(o[6], o[7]);
    float sl = 0.f, sr = 0.f;
#pragma unroll
    for (int j = 0; j < 8; j++) { sl += o[j] * attL[j]; sr += o[j] * attR[j]; }
    sl += __shfl_xor(sl, 1, 64);
    sr += __shfl_xor(sr, 1, 64);
    if (!(tx & 1)) { aL[n * 8 + hd] = sl; aR[n * 8 + hd] = sr; }
  }
}

// ---------- 128x128 GEMM, fused input BN+lrelu, h fp16, fused att dots ----------
#define GB_NODES 128
__global__ __launch_bounds__(256, 2)
void k_gemm128_bn(const float* __restrict__ y, const float* __restrict__ scale,
                  const float* __restrict__ shift, const float* __restrict__ W,
                  const float* __restrict__ att, __half* __restrict__ hh,
                  float* __restrict__ aL, float* __restrict__ aR) {
  __shared__ float sw[HID][HID + 4];
  __shared__ float sscale[HID], sshift[HID];
  int tid = threadIdx.x;
  if (tid < HID) { sscale[tid] = scale[tid]; sshift[tid] = shift[tid]; }
  for (int idx = tid * 4; idx < HID * HID; idx += 256 * 4) {
    int c = idx >> 7, k = idx & 127;
    float4 w = *(const float4*)(W + (size_t)c * HID + k);
    sw[k + 0][c] = w.x; sw[k + 1][c] = w.y; sw[k + 2][c] = w.z; sw[k + 3][c] = w.w;
  }
  __syncthreads();
  int tx = tid & 15, ty = tid >> 4;
  int n0 = blockIdx.x * GB_NODES + ty * 8;
  int c0 = tx * 8;
  int hd = tx >> 1;
  int k0 = (tx & 1) * 8;
  float attL[8], attR[8];
#pragma unroll
  for (int j = 0; j < 8; j++) {
    attL[j] = att[hd * 2 * KH + k0 + j];
    attR[j] = att[hd * 2 * KH + KH + k0 + j];
  }
  float acc[8][8];
#pragma unroll
  for (int i = 0; i < 8; i++)
#pragma unroll
    for (int j = 0; j < 8; j++) acc[i][j] = 0.f;

  const float* xp = y + (size_t)n0 * HID;
  for (int kk = 0; kk < HID; kk += 4) {
    float4 sc = *(const float4*)&sscale[kk];
    float4 sh = *(const float4*)&sshift[kk];
    float4 xv[8];
#pragma unroll
    for (int i = 0; i < 8; i++) {
      float4 v = *(const float4*)(xp + (size_t)i * HID + kk);
      v.x = lrelu(v.x * sc.x + sh.x);
      v.y = lrelu(v.y * sc.y + sh.y);
      v.z = lrelu(v.z * sc.z + sh.z);
      v.w = lrelu(v.w * sc.w + sh.w);
      xv[i] = v;
    }
#pragma unroll
    for (int k4 = 0; k4 < 4; k4++) {
      float4 w0 = *(const float4*)&sw[kk + k4][c0];
      float4 w1 = *(const float4*)&sw[kk + k4][c0 + 4];
      float wj[8] = { w0.x, w0.y, w0.z, w0.w, w1.x, w1.y, w1.z, w1.w };
#pragma unroll
      for (int i = 0; i < 8; i++) {
        const float* xe = (const float*)&xv[i];
        float xs = xe[k4];
#pragma unroll
        for (int j = 0; j < 8; j++) acc[i][j] += xs * wj[j];
      }
    }
  }
#pragma unroll
  for (int i = 0; i < 8; i++) {
    __half2* hp = (__half2*)(hh + (size_t)(n0 + i) * HID + c0);
    hp[0] = __floats2half2_rn(acc[i][0], acc[i][1]);
    hp[1] = __floats2half2_rn(acc[i][2], acc[i][3]);
    hp[2] = __floats2half2_rn(acc[i][4], acc[i][5]);
    hp[3] = __floats2half2_rn(acc[i][6], acc[i][7]);
    float sl = 0.f, sr = 0.f;
#pragma unroll
    for (int j = 0; j < 8; j++) { sl += acc[i][j] * attL[j]; sr += acc[i][j] * attR[j]; }
    sl += __shfl_xor(sl, 1, 64);
    sr += __shfl_xor(sr, 1, 64);
    if (!(tx & 1)) { aL[(n0 + i) * 8 + hd] = sl; aR[(n0 + i) * 8 + hd] = sr; }
  }
}

// per (node, head): online softmax stats over flat out-edge array
__global__ void k_src_softmax(const int* __restrict__ degS, const int* __restrict__ flatS,
                              const float* __restrict__ aL, const float* __restrict__ aR,
                              float4* __restrict__ pk) {
  int t = blockIdx.x * blockDim.x + threadIdx.x;
  int n = t >> 3;
  if (n >= NNODES) return;
  int hd = t & 7;
  int sh = n * 8 + hd;
  float aRn = aR[sh];
  float aself_a = lrelu(aL[sh] + aRn);
  float m = aself_a, l = 1.f;
  const int* fb = flatS + ((size_t)n << 6);
  int deg = degS[n];
  int j = 0;
  for (; j + 1 < deg; j += 2) {
    int d0 = fb[j], d1 = fb[j + 1];
    float a0 = lrelu(aL[d0 * 8 + hd] + aRn);
    float a1 = lrelu(aL[d1 * 8 + hd] + aRn);
    if (a0 > m) { l = l * __expf(m - a0) + 1.f; m = a0; } else l += __expf(a0 - m);
    if (a1 > m) { l = l * __expf(m - a1) + 1.f; m = a1; } else l += __expf(a1 - m);
  }
  if (j < deg) {
    float a0 = lrelu(aL[fb[j] * 8 + hd] + aRn);
    if (a0 > m) { l = l * __expf(m - a0) + 1.f; m = a0; } else l += __expf(a0 - m);
  }
  float rinv = 1.f / (l + 1e-16f);
  pk[sh] = make_float4(aRn, m, rinv, __expf(aself_a - m) * rinv);
}

// gather via flat dst arrays; 32 thr/node, 4 ch/thr; grid-stride; fused BN partials
__global__ __launch_bounds__(256)
void k_agg_gather(const int* __restrict__ degD, const int* __restrict__ flatD,
                  const float4* __restrict__ pk, const float* __restrict__ aL,
                  const float2* __restrict__ hh4, const float4* __restrict__ bias4,
                  float* __restrict__ yout, float* __restrict__ binS,
                  float* __restrict__ binQ) {
  int slot = threadIdx.x >> 5;
  int c = threadIdx.x & 31;
  int hd = c >> 2;
  float4 bb = bias4[c];
  float s0 = 0.f, s1 = 0.f, s2 = 0.f, s3 = 0.f;
  float q0 = 0.f, q1 = 0.f, q2 = 0.f, q3 = 0.f;
  for (int ng = blockIdx.x; ng < NNODES / 8; ng += gridDim.x) {
    int node = ng * 8 + slot;
    float aln = aL[node * 8 + hd];
    float4 pkn = pk[node * 8 + hd];
    float2 raw = hh4[(size_t)node * 32 + c];
    __half2 rl = *(__half2*)&raw.x, rh = *(__half2*)&raw.y;
    float2 f0 = __half22float2(rl), f1 = __half22float2(rh);
    float a0 = pkn.w * f0.x, a1 = pkn.w * f0.y, a2 = pkn.w * f1.x, a3 = pkn.w * f1.y;
    const int* fb = flatD + ((size_t)node << 6);
    int deg = degD[node];
    int j = 0;
    for (; j + 1 < deg; j += 2) {
      int sa = fb[j], sb = fb[j + 1];
      float4 qa = pk[sa * 8 + hd];
      float4 qb = pk[sb * 8 + hd];
      float2 ra = hh4[(size_t)sa * 32 + c];
      float2 rb = hh4[(size_t)sb * 32 + c];
      float ala = __expf(lrelu(aln + qa.x) - qa.y) * qa.z;
      float alb = __expf(lrelu(aln + qb.x) - qb.y) * qb.z;
      __half2 ral = *(__half2*)&ra.x, rah = *(__half2*)&ra.y;
      __half2 rbl = *(__half2*)&rb.x, rbh = *(__half2*)&rb.y;
      float2 g0 = __half22float2(ral), g1 = __half22float2(rah);
      float2 g2 = __half22float2(rbl), g3 = __half22float2(rbh);
      a0 += ala * g0.x + alb * g2.x;
      a1 += ala * g0.y + alb * g2.y;
      a2 += ala * g1.x + alb * g3.x;
      a3 += ala * g1.y + alb * g3.y;
    }
    if (j < deg) {
      int sa = fb[j];
      float4 qa = pk[sa * 8 + hd];
      float2 ra = hh4[(size_t)sa * 32 + c];
      float ala = __expf(lrelu(aln + qa.x) - qa.y) * qa.z;
      __half2 ral = *(__half2*)&ra.x, rah = *(__half2*)&ra.y;
      float2 g0 = __half22float2(ral), g1 = __half22float2(rah);
      a0 += ala * g0.x; a1 += ala * g0.y; a2 += ala * g1.x; a3 += ala * g1.y;
    }
    float4 v = make_float4(a0 + bb.x, a1 + bb.y, a2 + bb.z, a3 + bb.w);
    v.x = v.x > 0.f ? v.x : 0.f;
    v.y = v.y > 0.f ? v.y : 0.f;
    v.z = v.z > 0.f ? v.z : 0.f;
    v.w = v.w > 0.f ? v.w : 0.f;
    *(float4*)(yout + (size_t)node * HID + c * 4) = v;
    s0 += v.x; s1 += v.y; s2 += v.z; s3 += v.w;
    q0 += v.x * v.x; q1 += v.y * v.y; q2 += v.z * v.z; q3 += v.w * v.w;
  }
  // combine the two slots within each wave (lane ^ 32 has same c)
  s0 += __shfl_xor(s0, 32, 64); s1 += __shfl_xor(s1, 32, 64);
  s2 += __shfl_xor(s2, 32, 64); s3 += __shfl_xor(s3, 32, 64);
  q0 += __shfl_xor(q0, 32, 64); q1 += __shfl_xor(q1, 32, 64);
  q2 += __shfl_xor(q2, 32, 64); q3 += __shfl_xor(q3, 32, 64);
  __shared__ float ls[4][32][4], lq[4][32][4];
  int wv = threadIdx.x >> 6;
  if ((threadIdx.x & 63) < 32) {
    ls[wv][c][0] = s0; ls[wv][c][1] = s1; ls[wv][c][2] = s2; ls[wv][c][3] = s3;
    lq[wv][c][0] = q0; lq[wv][c][1] = q1; lq[wv][c][2] = q2; lq[wv][c][3] = q3;
  }
  __syncthreads();
  if (threadIdx.x < HID) {
    int cc = threadIdx.x >> 2, ch = threadIdx.x & 3;
    float ts = 0.f, tq = 0.f;
#pragma unroll
    for (int w = 0; w < 4; w++) { ts += ls[w][cc][ch]; tq += lq[w][cc][ch]; }
    int bin = blockIdx.x & (NBINS - 1);
    atomicAdd(&binS[bin * HID + threadIdx.x], ts);
    atomicAdd(&binQ[bin * HID + threadIdx.x], tq);
  }
}

// reduce bins -> scale/shift; then zero bins for the next layer
__global__ void k_bnfinal(const float* __restrict__ binS, const float* __restrict__ binQ,
                          const float* __restrict__ g, const float* __restrict__ be,
                          float* __restrict__ scale, float* __restrict__ shift,
                          float* __restrict__ binSw, float* __restrict__ binQw) {
  int c = threadIdx.x;
  double s = 0.0, q = 0.0;
#pragma unroll
  for (int b = 0; b < NBINS; b++) { s += (double)binS[b * HID + c]; q += (double)binQ[b * HID + c]; }
  double mean = s / (double)NNODES;
  double var  = q / (double)NNODES - mean * mean;
  float rs = (float)(1.0 / sqrt(var + (double)EPSBN));
  float sc = g[c] * rs;
  scale[c] = sc;
  shift[c] = be[c] - (float)mean * sc;
  __syncthreads();
#pragma unroll
  for (int b = 0; b < NBINS; b++) { binSw[b * HID + c] = 0.f; binQw[b * HID + c] = 0.f; }
}

// power-mean partial sums with fused BN+lrelu (layer-3 BN applied here)
__global__ void k_pmean_bn(const float* __restrict__ y, const float* __restrict__ scale,
                           const float* __restrict__ shift, const float* __restrict__ p_,
                           float* __restrict__ xgsum) {
  int b = blockIdx.y, c = threadIdx.x;
  float p = p_[0];
  float sc = scale[c], sh = shift[c];
  int rows_per = (PERB + gridDim.x - 1) / gridDim.x;
  int r0 = blockIdx.x * rows_per;
  int r1 = r0 + rows_per; if (r1 > PERB) r1 = PERB;
  float acc = 0.f;
  for (int i = r0; i < r1; i++) {
    float v = y[((size_t)b * PERB + i) * HID + c];
    v = lrelu(v * sc + sh);
    v = fminf(fmaxf(v, 0.f), 100.f);
    acc += powf(v, p);
  }
  atomicAdd(&xgsum[b * HID + c], acc);
}

__global__ void k_head(const float* __restrict__ xgsum, const float* __restrict__ p_,
                       const float* __restrict__ Wg, const float* __restrict__ bg,
                       float* __restrict__ out) {
  __shared__ float sxg[HID];
  __shared__ float red[HID];
  int b = blockIdx.x, c = threadIdx.x;
  float p = p_[0];
  float m = xgsum[b * HID + c] / (float)PERB;
  m = fminf(fmaxf(m, 0.f), 100.f);
  sxg[c] = powf(m, 1.0f / p);
  __syncthreads();
  float l0 = 0.f, l1 = 0.f;
  for (int j = 0; j < 2; j++) {
    red[c] = sxg[c] * Wg[j * HID + c];
    __syncthreads();
    for (int off = 64; off > 0; off >>= 1) {
      if (c < off) red[c] += red[c + off];
      __syncthreads();
    }
    if (c == 0) { if (j == 0) l0 = red[0] + bg[0]; else l1 = red[0] + bg[1]; }
    __syncthreads();
  }
  if (c == 0) {
    out[b * 2 + 0] = l0;
    out[b * 2 + 1] = l1;
    out[2 * BATCH + b] = (l1 > l0) ? 1.0f : 0.0f;
  }
}

extern "C" void kernel_launch(void* const* d_in, const int* in_sizes, int n_in,
                              void* d_out, int out_size, void* d_ws, size_t ws_size,
                              hipStream_t stream) {
  (void)in_sizes; (void)n_in; (void)out_size; (void)ws_size;
  const float* x    = (const float*)d_in[0];
  const int*   ei   = (const int*)d_in[1];
  const float* Wl[3]   = { (const float*)d_in[2],  (const float*)d_in[7],  (const float*)d_in[12] };
  const float* attl[3] = { (const float*)d_in[3],  (const float*)d_in[8],  (const float*)d_in[13] };
  const float* bl[3]   = { (const float*)d_in[4],  (const float*)d_in[9],  (const float*)d_in[14] };
  const float* gl[3]   = { (const float*)d_in[5],  (const float*)d_in[10], (const float*)d_in[15] };
  const float* bel[3]  = { (const float*)d_in[6],  (const float*)d_in[11], (const float*)d_in[16] };
  const float* p    = (const float*)d_in[17];
  const float* Wg   = (const float*)d_in[18];
  const float* bg   = (const float*)d_in[19];
  float* out = (float*)d_out;

  float* ws   = (float*)d_ws;
  __half* hh  = (__half*)ws;                         // N*128 halfs = N*64 floats
  float* agg  = ws + (size_t)NNODES * (HID / 2);     // N*128 floats (= y, pre-BN)
  float* aL   = agg + (size_t)NNODES * HID;          // N*8
  float* aR   = aL  + (size_t)NNODES * HEADS;        // N*8
  float4* pk  = (float4*)(aR + (size_t)NNODES * HEADS);  // N*8 float4
  float* binS = (float*)(pk + (size_t)NNODES * HEADS);   // NBINS*128
  float* binQ = binS + NBINS * HID;
  float* scale  = binQ + NBINS * HID;
  float* shift  = scale + HID;
  float* xgsum  = shift + HID;                       // 8*128
  int2* next2D  = (int2*)(xgsum + BATCH * HID);      // NEDGE {next, src}
  int2* next2S  = next2D + NEDGE;                    // NEDGE {next, dst}
  int* headD    = (int*)(next2S + NEDGE);            // N
  int* headS    = headD + NNODES;                    // N
  int* degD     = headS + NNODES;                    // N
  int* degS     = degD + NNODES;                     // N
  int* flatD    = degS + NNODES;                     // N*64
  int* flatS    = flatD + (size_t)NNODES * 64;       // N*64

  // ---- build linked lists then flatten to padded arrays ----
  hipMemsetAsync(headD, 0xFF, sizeof(int) * 2 * NNODES, stream);
  hipMemsetAsync(binS, 0, sizeof(float) * 2 * NBINS * HID, stream);
  k_link<<<(NEDGE + 255) / 256, 256, 0, stream>>>(ei, headD, headS, next2D, next2S);
  k_flatten<<<(2 * NNODES + 255) / 256, 256, 0, stream>>>(headD, next2D, headS, next2S,
                                                          flatD, degD, flatS, degS);

  for (int layer = 0; layer < 3; layer++) {
    if (layer == 0)
      k_gemm_in<<<2048, 256, 0, stream>>>(x, Wl[0], attl[0], hh, aL, aR);
    else
      k_gemm128_bn<<<NNODES / GB_NODES, 256, 0, stream>>>(agg, scale, shift, Wl[layer],
                                                          attl[layer], hh, aL, aR);

    k_src_softmax<<<(NNODES * 8 + 255) / 256, 256, 0, stream>>>(degS, flatS, aL, aR, pk);
    k_agg_gather<<<GGRID, 256, 0, stream>>>(degD, flatD, pk, aL, (const float2*)hh,
                                            (const float4*)bl[layer], agg, binS, binQ);
    k_bnfinal<<<1, HID, 0, stream>>>(binS, binQ, gl[layer], bel[layer], scale, shift,
                                     binS, binQ);
  }

  hipMemsetAsync(xgsum, 0, sizeof(float) * BATCH * HID, stream);
  k_pmean_bn<<<dim3(256, BATCH), 128, 0, stream>>>(agg, scale, shift, p, xgsum);
  k_head<<<BATCH, 128, 0, stream>>>(xgsum, p, Wg, bg, out);
}